// Round 5
// baseline (6556.248 us; speedup 1.0000x reference)
//
#include <hip/hip_runtime.h>
#include <cmath>
#include <cstdint>

#define VOCAB 32000
#define HID   1024
#define BATCH 16
#define SEQ   256
#define NBLK  192

typedef __attribute__((ext_vector_type(8))) short short8;
typedef __attribute__((ext_vector_type(4))) float f32x4;

__device__ __forceinline__ ushort f2bf(float f) {  // RNE fp32 -> bf16 bits
  uint u = __builtin_bit_cast(uint, f);
  return (ushort)((u + 0x7FFFu + ((u >> 16) & 1u)) >> 16);
}
__device__ __forceinline__ float bf2f(ushort h) {
  return __builtin_bit_cast(float, (uint)h << 16);
}

// agent-scope cache-bypassing accessors (no wbl2/inv cache maintenance)
__device__ __forceinline__ float agload(const float* p) {
  return __hip_atomic_load(p, __ATOMIC_RELAXED, __HIP_MEMORY_SCOPE_AGENT);
}
__device__ __forceinline__ void agstore(float* p, float v) {
  __hip_atomic_store(p, v, __ATOMIC_RELAXED, __HIP_MEMORY_SCOPE_AGENT);
}

// ---------------------------------------------------------------------------
// pre0[t][b][n] = embed[x[b][t]] . Wi0[n] + bi0[n] + bh0[n]
// M=4096 (m=t*16+b), N=1024, K=1024. fp32 tiled GEMM (unchanged).
// ---------------------------------------------------------------------------
__global__ __launch_bounds__(256) void pre0_gemm(
    const int* __restrict__ x, const float* __restrict__ embed,
    const float* __restrict__ Wi0, const float* __restrict__ bi0,
    const float* __restrict__ bh0, float* __restrict__ pre)
{
  __shared__ float As[32][132];
  __shared__ float Bs[32][132];
  const int tid  = threadIdx.x;
  const int n0   = blockIdx.x * 128;
  const int m0   = blockIdx.y * 128;
  const int lrow = tid >> 3, lkq = tid & 7;
  const int ty   = tid >> 4, tx  = tid & 15;

  const float* arow[4];
#pragma unroll
  for (int q = 0; q < 4; ++q) {
    int m = m0 + lrow + 32 * q;
    int t = m >> 4, b = m & 15;
    arow[q] = embed + (size_t)x[b * SEQ + t] * HID;
  }
  const float* brow = Wi0 + (size_t)(n0 + lrow) * HID;

  float acc[8][8];
#pragma unroll
  for (int i = 0; i < 8; ++i)
#pragma unroll
    for (int j = 0; j < 8; ++j) acc[i][j] = 0.f;

  for (int kt = 0; kt < HID; kt += 32) {
    float4 av[4], bv[4];
#pragma unroll
    for (int q = 0; q < 4; ++q) {
      av[q] = *(const float4*)(arow[q] + kt + lkq * 4);
      bv[q] = *(const float4*)(brow + (size_t)(32 * q) * HID + kt + lkq * 4);
    }
    __syncthreads();
#pragma unroll
    for (int q = 0; q < 4; ++q) {
      int r = lrow + 32 * q;
      As[lkq*4+0][r] = av[q].x; As[lkq*4+1][r] = av[q].y;
      As[lkq*4+2][r] = av[q].z; As[lkq*4+3][r] = av[q].w;
      Bs[lkq*4+0][r] = bv[q].x; Bs[lkq*4+1][r] = bv[q].y;
      Bs[lkq*4+2][r] = bv[q].z; Bs[lkq*4+3][r] = bv[q].w;
    }
    __syncthreads();
#pragma unroll
    for (int kk = 0; kk < 32; ++kk) {
      float4 a0 = *(const float4*)&As[kk][ty * 8];
      float4 a1 = *(const float4*)&As[kk][ty * 8 + 4];
      float4 b0 = *(const float4*)&Bs[kk][tx * 8];
      float4 b1 = *(const float4*)&Bs[kk][tx * 8 + 4];
      float a[8] = {a0.x,a0.y,a0.z,a0.w,a1.x,a1.y,a1.z,a1.w};
      float b[8] = {b0.x,b0.y,b0.z,b0.w,b1.x,b1.y,b1.z,b1.w};
#pragma unroll
      for (int i = 0; i < 8; ++i)
#pragma unroll
        for (int j = 0; j < 8; ++j) acc[i][j] = fmaf(a[i], b[j], acc[i][j]);
    }
  }

#pragma unroll
  for (int i = 0; i < 8; ++i) {
    int m = m0 + ty * 8 + i;
    float* o = pre + (size_t)m * HID + n0 + tx * 8;
#pragma unroll
    for (int j = 0; j < 8; ++j) {
      int n = n0 + tx * 8 + j;
      o[j] = acc[i][j] + bi0[n] + bh0[n];
    }
  }
}

// ---------------------------------------------------------------------------
// Fused skewed cooperative scan. Cross-block h traffic via agent-scope
// relaxed atomics (cache-bypassing, coherent at IF — no wbl2/inv per tick).
// Barrier: relaxed fetch_add + relaxed spin; __syncthreads() drains each
// wave's stores (compiler emits vmcnt(0) before s_barrier) before arrival.
//  Blocks 0..63  (L0): 16 rows of Wh0 in LDS;  tick u<256 computes h0[u].
//  Blocks 64..191 (L1): 8 rows of [Wi1|Wh1];   tick u>=1 computes h1[u-1].
// ---------------------------------------------------------------------------
__global__ __launch_bounds__(512) void rnn_scan(
    const float* __restrict__ Wi, const float* __restrict__ Wh,
    const float* __restrict__ bi, const float* __restrict__ bh,
    const float* __restrict__ pre0, float* __restrict__ h0g,
    float* __restrict__ h1g, float* __restrict__ tops,
    int* __restrict__ bar)
{
  __shared__ float wT[16 * 1024];   // L0: [k][16]; L1: [k2][8], k2<2048
  __shared__ float hT[1024 * 16];   // [k][16] staged h
  __shared__ float part[2048];
  __shared__ float bias[8];

  const int tid = threadIdx.x;
  const int blk = blockIdx.x;
  const bool isL0 = (blk < 64);

  // ---- one-time: load transposed weights into LDS ----
  if (isL0) {
    const int j = blk;                       // rows 16j..16j+15 of Wh0
#pragma unroll
    for (int p = 0; p < 8; ++p) {
      int idx = tid + 512 * p;               // float4 index 0..4095
      int r = idx >> 8, kq = idx & 255;
      float4 v = *(const float4*)(Wh + ((size_t)(16 * j + r)) * HID + 4 * kq);
      wT[(4*kq+0)*16 + r] = v.x; wT[(4*kq+1)*16 + r] = v.y;
      wT[(4*kq+2)*16 + r] = v.z; wT[(4*kq+3)*16 + r] = v.w;
    }
  } else {
    const int j = blk - 64;                  // rows 8j..8j+7
#pragma unroll
    for (int p = 0; p < 8; ++p) {
      int idx = tid + 512 * p;               // 0..4095; first half Wi1, rest Wh1
      int half = idx >> 11;
      int id2 = idx & 2047;
      int r = id2 >> 8, kq = id2 & 255;
      const float* W = (half ? Wh : Wi) + (size_t)HID * HID;
      float4 v = *(const float4*)(W + ((size_t)(8 * j + r)) * HID + 4 * kq);
      int kb = half * 1024 + 4 * kq;
      wT[(kb+0)*8 + r] = v.x; wT[(kb+1)*8 + r] = v.y;
      wT[(kb+2)*8 + r] = v.z; wT[(kb+3)*8 + r] = v.w;
    }
    if (tid < 8) bias[tid] = bi[HID + 8 * j + tid] + bh[HID + 8 * j + tid];
  }
  __syncthreads();

  // stage 16x1024 h (global [b][k], coherent loads) into registers
  auto stage_load = [&](const float* src, float* r) {
#pragma unroll
    for (int p = 0; p < 8; ++p) {
      int i = tid + 512 * p;                 // float4 index 0..4095
      int b = i & 15, kq = i >> 4;
      const float* q = src + (size_t)b * HID + 4 * kq;
#pragma unroll
      for (int c = 0; c < 4; ++c) r[4*p+c] = agload(q + c);
    }
  };
  auto stage_write = [&](const float* r) {
#pragma unroll
    for (int p = 0; p < 8; ++p) {
      int i = tid + 512 * p;
      int b = i & 15, kq = i >> 4;
#pragma unroll
      for (int c = 0; c < 4; ++c) hT[(4*kq+c)*16 + b] = r[4*p+c];
    }
  };

  for (int u = 0; u <= SEQ; ++u) {
    if (isL0) {
      if (u < SEQ) {
        float r0[32];
        stage_load(h0g + ((u - 1) & 1) * (BATCH * HID), r0);
        stage_write(r0);
        __syncthreads();
        const int bq = tid & 3, rq = (tid >> 2) & 3, ks = tid >> 4;  // ks 0..31
        float acc[4][4] = {{0.f}};
#pragma unroll 4
        for (int i = 0; i < 32; ++i) {
          int k = ks + 32 * i;
          float4 hv = *(const float4*)&hT[k * 16 + 4 * bq];
          float4 wv = *(const float4*)&wT[k * 16 + 4 * rq];
          float hb[4] = {hv.x, hv.y, hv.z, hv.w};
          float wr[4] = {wv.x, wv.y, wv.z, wv.w};
#pragma unroll
          for (int bi_ = 0; bi_ < 4; ++bi_)
#pragma unroll
            for (int rj = 0; rj < 4; ++rj)
              acc[bi_][rj] = fmaf(hb[bi_], wr[rj], acc[bi_][rj]);
        }
#pragma unroll
        for (int bi_ = 0; bi_ < 4; ++bi_)
#pragma unroll
          for (int rj = 0; rj < 4; ++rj) {
            float v = acc[bi_][rj];
            v += __shfl_xor(v, 16); v += __shfl_xor(v, 32);
            acc[bi_][rj] = v;
          }
        const int w = tid >> 6;
        if ((tid & 63) < 16) {
#pragma unroll
          for (int bi_ = 0; bi_ < 4; ++bi_)
#pragma unroll
            for (int rj = 0; rj < 4; ++rj)
              part[w * 256 + (4*bq + bi_) * 16 + 4*rq + rj] = acc[bi_][rj];
        }
        __syncthreads();
        if (tid < 256) {
          int b = tid >> 4, r = tid & 15;
          float s = 0.f;
#pragma unroll
          for (int w2 = 0; w2 < 8; ++w2) s += part[w2 * 256 + b * 16 + r];
          int R = 16 * blk + r;
          s += pre0[((size_t)u * BATCH + b) * HID + R];
          float v = tanhf(s);
          agstore(h0g + (u & 1) * (BATCH * HID) + (size_t)b * HID + R, v);
        }
      }
    } else {
      if (u >= 1) {
        const int t = u - 1;
        const int bq = tid & 3, rq = (tid >> 2) & 1, ks = tid >> 3;  // ks 0..63
        float acc[4][4] = {{0.f}};
        float r0[32], r1[32];
        stage_load(h0g + (t & 1) * (BATCH * HID), r0);          // both loads
        stage_load(h1g + ((t - 1) & 1) * (BATCH * HID), r1);    // in flight
        stage_write(r0);
        __syncthreads();
        // phase A: Wi1 . h0[t]
#pragma unroll 4
        for (int i = 0; i < 16; ++i) {
          int k = ks + 64 * i;
          float4 hv = *(const float4*)&hT[k * 16 + 4 * bq];
          float4 wv = *(const float4*)&wT[k * 8 + 4 * rq];
          float hb[4] = {hv.x, hv.y, hv.z, hv.w};
          float wr[4] = {wv.x, wv.y, wv.z, wv.w};
#pragma unroll
          for (int bi_ = 0; bi_ < 4; ++bi_)
#pragma unroll
            for (int rj = 0; rj < 4; ++rj)
              acc[bi_][rj] = fmaf(hb[bi_], wr[rj], acc[bi_][rj]);
        }
        __syncthreads();   // done reading hT
        stage_write(r1);
        __syncthreads();
        // phase B: Wh1 . h1[t-1]
#pragma unroll 4
        for (int i = 0; i < 16; ++i) {
          int k = ks + 64 * i;
          float4 hv = *(const float4*)&hT[k * 16 + 4 * bq];
          float4 wv = *(const float4*)&wT[(1024 + k) * 8 + 4 * rq];
          float hb[4] = {hv.x, hv.y, hv.z, hv.w};
          float wr[4] = {wv.x, wv.y, wv.z, wv.w};
#pragma unroll
          for (int bi_ = 0; bi_ < 4; ++bi_)
#pragma unroll
            for (int rj = 0; rj < 4; ++rj)
              acc[bi_][rj] = fmaf(hb[bi_], wr[rj], acc[bi_][rj]);
        }
#pragma unroll
        for (int bi_ = 0; bi_ < 4; ++bi_)
#pragma unroll
          for (int rj = 0; rj < 4; ++rj) {
            float v = acc[bi_][rj];
            v += __shfl_xor(v, 8); v += __shfl_xor(v, 16); v += __shfl_xor(v, 32);
            acc[bi_][rj] = v;
          }
        const int w = tid >> 6;
        if ((tid & 63) < 8) {
#pragma unroll
          for (int bi_ = 0; bi_ < 4; ++bi_)
#pragma unroll
            for (int rj = 0; rj < 4; ++rj)
              part[w * 128 + (4*bq + bi_) * 8 + 4*rq + rj] = acc[bi_][rj];
        }
        __syncthreads();
        if (tid < 128) {
          int b = tid >> 3, r = tid & 7;
          float s = bias[r];
#pragma unroll
          for (int w2 = 0; w2 < 8; ++w2) s += part[w2 * 128 + b * 8 + r];
          int R = 8 * (blk - 64) + r;
          float v = tanhf(s);
          tops[((size_t)t * BATCH + b) * HID + R] = v;   // plain: read after kernel
          agstore(h1g + (t & 1) * (BATCH * HID) + (size_t)b * HID + R, v);
        }
      }
    }

    // ---- barrier: relaxed add + relaxed spin (no cache maintenance) ----
    __syncthreads();   // drains each wave's stores (vmcnt(0) before s_barrier)
    if (tid == 0) {
      __hip_atomic_fetch_add(bar, 1, __ATOMIC_RELAXED, __HIP_MEMORY_SCOPE_AGENT);
      const int target = NBLK * (u + 1);
      while (__hip_atomic_load(bar, __ATOMIC_RELAXED, __HIP_MEMORY_SCOPE_AGENT) < target)
        __builtin_amdgcn_s_sleep(2);
    }
    __syncthreads();
    asm volatile("" ::: "memory");
  }
}

// ---------------------------------------------------------------------------
// logits = tops . Wo^T + bo via split-bf16 MFMA (A = hi+lo, B = bf16).
// C[m][n], m=b*256+s, M=4096, N=32000, K=1024. BM=BN=256, BK=64.
// 512 thr = 8 waves as 4m x 2n, wave tile 64x128 (4x8 16x16 frags).
// ---------------------------------------------------------------------------
__global__ __launch_bounds__(512, 1) void proj_mfma(
    const float* __restrict__ tops, const float* __restrict__ Wo,
    const float* __restrict__ bo, float* __restrict__ out)
{
  __shared__ ushort Ahi[256 * 64];
  __shared__ ushort Alo[256 * 64];
  __shared__ ushort Bs [256 * 64];
  const int tid  = threadIdx.x;
  const int m0   = blockIdx.x * 256;    // 16 M-blocks (fastest: share B panel)
  const int n0   = blockIdx.y * 256;    // 125 N-blocks
  const int lane = tid & 63, wv = tid >> 6;
  const int wm   = wv & 3, wn = wv >> 2;
  const int bconst = blockIdx.x;        // batch index for all rows of this block

  f32x4 acc[4][8];
#pragma unroll
  for (int i = 0; i < 4; ++i)
#pragma unroll
    for (int j = 0; j < 8; ++j) acc[i][j] = (f32x4)0.f;

  const int sr = tid >> 4;              // staging row base 0..31
  const int sk = (tid & 15) * 4;        // staging k offset 0..60

  for (int kt = 0; kt < HID; kt += 64) {
    __syncthreads();
#pragma unroll
    for (int p = 0; p < 8; ++p) {       // stage A (tops rows, split hi/lo)
      int r = sr + 32 * p;              // 0..255 ; s=r, b=bconst
      float4 v = *(const float4*)(tops + ((size_t)r * BATCH + bconst) * HID + kt + sk);
      float f[4] = {v.x, v.y, v.z, v.w};
      ushort hi[4], lo[4];
#pragma unroll
      for (int c = 0; c < 4; ++c) {
        hi[c] = f2bf(f[c]);
        lo[c] = f2bf(f[c] - bf2f(hi[c]));
      }
      uint off = (uint)(r * 128 + sk * 2) ^ (uint)((r & 7) << 4);
      *(ushort4*)((char*)Ahi + off) = make_ushort4(hi[0], hi[1], hi[2], hi[3]);
      *(ushort4*)((char*)Alo + off) = make_ushort4(lo[0], lo[1], lo[2], lo[3]);
    }
#pragma unroll
    for (int p = 0; p < 8; ++p) {       // stage B (Wo rows -> bf16)
      int r = sr + 32 * p;
      float4 v = *(const float4*)(Wo + (size_t)(n0 + r) * HID + kt + sk);
      uint off = (uint)(r * 128 + sk * 2) ^ (uint)((r & 7) << 4);
      *(ushort4*)((char*)Bs + off) =
          make_ushort4(f2bf(v.x), f2bf(v.y), f2bf(v.z), f2bf(v.w));
    }
    __syncthreads();

    const int fr = lane & 15, kg = lane >> 4;
#pragma unroll
    for (int kk = 0; kk < 2; ++kk) {
      short8 bf[8], ah[4], al[4];
#pragma unroll
      for (int nf = 0; nf < 8; ++nf) {
        int row = wn * 128 + nf * 16 + fr;
        uint off = (uint)(row * 128 + kk * 64 + kg * 16) ^ (uint)((row & 7) << 4);
        bf[nf] = *(const short8*)((const char*)Bs + off);
      }
#pragma unroll
      for (int mf = 0; mf < 4; ++mf) {
        int row = wm * 64 + mf * 16 + fr;
        uint off = (uint)(row * 128 + kk * 64 + kg * 16) ^ (uint)((row & 7) << 4);
        ah[mf] = *(const short8*)((const char*)Ahi + off);
        al[mf] = *(const short8*)((const char*)Alo + off);
      }
#pragma unroll
      for (int mf = 0; mf < 4; ++mf)
#pragma unroll
        for (int nf = 0; nf < 8; ++nf) {
          acc[mf][nf] = __builtin_amdgcn_mfma_f32_16x16x32_bf16(
              ah[mf], bf[nf], acc[mf][nf], 0, 0, 0);
          acc[mf][nf] = __builtin_amdgcn_mfma_f32_16x16x32_bf16(
              al[mf], bf[nf], acc[mf][nf], 0, 0, 0);
        }
    }
  }

  const int fr = lane & 15, rg = lane >> 4;
#pragma unroll
  for (int mf = 0; mf < 4; ++mf)
#pragma unroll
    for (int nf = 0; nf < 8; ++nf) {
      int n = n0 + wn * 128 + nf * 16 + fr;
      float bb = bo[n];
#pragma unroll
      for (int j = 0; j < 4; ++j) {
        int m = m0 + wm * 64 + mf * 16 + rg * 4 + j;
        out[(size_t)m * VOCAB + n] = acc[mf][nf][j] + bb;
      }
    }
}

// hidden[0][b][n] = h0 step 255 (parity 1); hidden[1][b][n] = tops[255]
__global__ void copy_hidden(const float* __restrict__ h0g,
                            const float* __restrict__ tops,
                            float* __restrict__ outh)
{
  int i = blockIdx.x * 256 + threadIdx.x;   // 0..32767
  int l = i >> 14, rem = i & 16383;
  outh[i] = (l == 0) ? h0g[BATCH * HID + rem]
                     : tops[(size_t)(SEQ - 1) * (BATCH * HID) + rem];
}

extern "C" void kernel_launch(void* const* d_in, const int* in_sizes, int n_in,
                              void* d_out, int out_size, void* d_ws, size_t ws_size,
                              hipStream_t stream)
{
  const int*   x     = (const int*)d_in[0];
  const float* embed = (const float*)d_in[1];
  const float* Wi    = (const float*)d_in[2];
  const float* bi    = (const float*)d_in[3];
  const float* Wh    = (const float*)d_in[4];
  const float* bh    = (const float*)d_in[5];
  const float* Wo    = (const float*)d_in[6];
  const float* bo    = (const float*)d_in[7];
  float* out = (float*)d_out;

  char* ws = (char*)d_ws;
  float* pre0 = (float*)(ws);                          // 16 MiB [t][b][n]
  float* tops = (float*)(ws + (16u << 20));            // 16 MiB [t][b][n]
  float* h0g  = (float*)(ws + (32u << 20));            // 2 x 64 KiB
  float* h1g  = (float*)(ws + (32u << 20) + 131072);   // 2 x 64 KiB
  int*   bar  = (int*)  (ws + (32u << 20) + 262144);   // barrier counter

  // zero h parities + barrier counter (deterministic across replays)
  hipMemsetAsync(h0g, 0, 262144 + 4096, stream);

  pre0_gemm<<<dim3(8, 32), dim3(256), 0, stream>>>(x, embed, Wi, bi, bh, pre0);

  void* args[] = { (void*)&Wi, (void*)&Wh, (void*)&bi, (void*)&bh,
                   (void*)&pre0, (void*)&h0g, (void*)&h1g, (void*)&tops,
                   (void*)&bar };
  hipLaunchCooperativeKernel((void*)rnn_scan, dim3(NBLK), dim3(512), args, 0, stream);

  proj_mfma<<<dim3(16, 125), dim3(512), 0, stream>>>(tops, Wo, bo, out);

  copy_hidden<<<dim3(128), dim3(256), 0, stream>>>(
      h0g, tops, out + (size_t)BATCH * SEQ * VOCAB);
}

// Round 7
// 4226.022 us; speedup vs baseline: 1.5514x; 1.5514x over previous
//
#include <hip/hip_runtime.h>
#include <cmath>
#include <cstdint>

#define VOCAB 32000
#define HID   1024
#define BATCH 16
#define SEQ   256
#define NBLK  192

typedef __attribute__((ext_vector_type(8))) short short8;
typedef __attribute__((ext_vector_type(4))) float f32x4;

__device__ __forceinline__ ushort f2bf(float f) {  // RNE fp32 -> bf16 bits
  uint u = __builtin_bit_cast(uint, f);
  return (ushort)((u + 0x7FFFu + ((u >> 16) & 1u)) >> 16);
}
__device__ __forceinline__ float bf2f(ushort h) {
  return __builtin_bit_cast(float, (uint)h << 16);
}

// ---- MALL-coherent vector load/store (sc0 sc1), no cache maintenance ------
// 8x dwordx4 from base + p*512B. EARLY-CLOBBER outputs: async returns must
// not overlap the base address pair (round-6 fault).
#define LOAD8(d, base)                                                        \
  asm volatile(                                                               \
    "global_load_dwordx4 %0, %8, off sc0 sc1\n\t"                             \
    "global_load_dwordx4 %1, %8, off offset:512 sc0 sc1\n\t"                  \
    "global_load_dwordx4 %2, %8, off offset:1024 sc0 sc1\n\t"                 \
    "global_load_dwordx4 %3, %8, off offset:1536 sc0 sc1\n\t"                 \
    "global_load_dwordx4 %4, %8, off offset:2048 sc0 sc1\n\t"                 \
    "global_load_dwordx4 %5, %8, off offset:2560 sc0 sc1\n\t"                 \
    "global_load_dwordx4 %6, %8, off offset:3072 sc0 sc1\n\t"                 \
    "global_load_dwordx4 %7, %8, off offset:3584 sc0 sc1"                     \
    : "=&v"(d[0]), "=&v"(d[1]), "=&v"(d[2]), "=&v"(d[3]),                     \
      "=&v"(d[4]), "=&v"(d[5]), "=&v"(d[6]), "=&v"(d[7])                      \
    : "v"(base) : "memory")

#define WAIT8(d)                                                              \
  asm volatile("s_waitcnt vmcnt(0)"                                           \
    : "+v"(d[0]), "+v"(d[1]), "+v"(d[2]), "+v"(d[3]),                         \
      "+v"(d[4]), "+v"(d[5]), "+v"(d[6]), "+v"(d[7]) :: "memory")

#define WAIT16(a, b)                                                          \
  asm volatile("s_waitcnt vmcnt(0)"                                           \
    : "+v"(a[0]), "+v"(a[1]), "+v"(a[2]), "+v"(a[3]),                         \
      "+v"(a[4]), "+v"(a[5]), "+v"(a[6]), "+v"(a[7]),                         \
      "+v"(b[0]), "+v"(b[1]), "+v"(b[2]), "+v"(b[3]),                         \
      "+v"(b[4]), "+v"(b[5]), "+v"(b[6]), "+v"(b[7]) :: "memory")

__device__ __forceinline__ void st_coherent(float* p, float v) {
  asm volatile("global_store_dword %0, %1, off sc0 sc1" :: "v"(p), "v"(v) : "memory");
}

// ---------------------------------------------------------------------------
// pre0[t][b][n] = embed[x[b][t]] . Wi0[n] + bi0[n] + bh0[n]   (unchanged)
// ---------------------------------------------------------------------------
__global__ __launch_bounds__(256) void pre0_gemm(
    const int* __restrict__ x, const float* __restrict__ embed,
    const float* __restrict__ Wi0, const float* __restrict__ bi0,
    const float* __restrict__ bh0, float* __restrict__ pre)
{
  __shared__ float As[32][132];
  __shared__ float Bs[32][132];
  const int tid  = threadIdx.x;
  const int n0   = blockIdx.x * 128;
  const int m0   = blockIdx.y * 128;
  const int lrow = tid >> 3, lkq = tid & 7;
  const int ty   = tid >> 4, tx  = tid & 15;

  const float* arow[4];
#pragma unroll
  for (int q = 0; q < 4; ++q) {
    int m = m0 + lrow + 32 * q;
    int t = m >> 4, b = m & 15;
    arow[q] = embed + (size_t)x[b * SEQ + t] * HID;
  }
  const float* brow = Wi0 + (size_t)(n0 + lrow) * HID;

  float acc[8][8];
#pragma unroll
  for (int i = 0; i < 8; ++i)
#pragma unroll
    for (int j = 0; j < 8; ++j) acc[i][j] = 0.f;

  for (int kt = 0; kt < HID; kt += 32) {
    float4 av[4], bv[4];
#pragma unroll
    for (int q = 0; q < 4; ++q) {
      av[q] = *(const float4*)(arow[q] + kt + lkq * 4);
      bv[q] = *(const float4*)(brow + (size_t)(32 * q) * HID + kt + lkq * 4);
    }
    __syncthreads();
#pragma unroll
    for (int q = 0; q < 4; ++q) {
      int r = lrow + 32 * q;
      As[lkq*4+0][r] = av[q].x; As[lkq*4+1][r] = av[q].y;
      As[lkq*4+2][r] = av[q].z; As[lkq*4+3][r] = av[q].w;
      Bs[lkq*4+0][r] = bv[q].x; Bs[lkq*4+1][r] = bv[q].y;
      Bs[lkq*4+2][r] = bv[q].z; Bs[lkq*4+3][r] = bv[q].w;
    }
    __syncthreads();
#pragma unroll
    for (int kk = 0; kk < 32; ++kk) {
      float4 a0 = *(const float4*)&As[kk][ty * 8];
      float4 a1 = *(const float4*)&As[kk][ty * 8 + 4];
      float4 b0 = *(const float4*)&Bs[kk][tx * 8];
      float4 b1 = *(const float4*)&Bs[kk][tx * 8 + 4];
      float a[8] = {a0.x,a0.y,a0.z,a0.w,a1.x,a1.y,a1.z,a1.w};
      float b[8] = {b0.x,b0.y,b0.z,b0.w,b1.x,b1.y,b1.z,b1.w};
#pragma unroll
      for (int i = 0; i < 8; ++i)
#pragma unroll
        for (int j = 0; j < 8; ++j) acc[i][j] = fmaf(a[i], b[j], acc[i][j]);
    }
  }

#pragma unroll
  for (int i = 0; i < 8; ++i) {
    int m = m0 + ty * 8 + i;
    float* o = pre + (size_t)m * HID + n0 + tx * 8;
#pragma unroll
    for (int j = 0; j < 8; ++j) {
      int n = n0 + tx * 8 + j;
      o[j] = acc[i][j] + bi0[n] + bh0[n];
    }
  }
}

// ---------------------------------------------------------------------------
// Fused skewed cooperative scan (round-4 control flow), relaxed barrier,
// h exchanged via sc0sc1 vector ops. No wbl2/inv anywhere.
//  Blocks 0..63  (L0): 16 rows Wh0 in LDS; tick u<256 computes h0[u].
//  Blocks 64..191 (L1): 8 rows [Wi1|Wh1]; tick u>=1 computes h1[u-1].
// h0g/h1g: [2][16][1024] parity double-buffers (pre-zeroed).
// ---------------------------------------------------------------------------
__global__ __launch_bounds__(512) void rnn_scan(
    const float* __restrict__ Wi, const float* __restrict__ Wh,
    const float* __restrict__ bi, const float* __restrict__ bh,
    const float* __restrict__ pre0, float* __restrict__ h0g,
    float* __restrict__ h1g, float* __restrict__ tops,
    int* __restrict__ bar)
{
  __shared__ float wT[16 * 1024];   // L0: [k][16]; L1: [k2][8], k2<2048
  __shared__ float hT[1024 * 16];   // [k][16] staged h
  __shared__ float part[2048];
  __shared__ float bias[8];

  const int tid = threadIdx.x;
  const int blk = blockIdx.x;
  const bool isL0 = (blk < 64);

  if (isL0) {
    const int j = blk;
#pragma unroll
    for (int p = 0; p < 8; ++p) {
      int idx = tid + 512 * p;
      int r = idx >> 8, kq = idx & 255;
      float4 v = *(const float4*)(Wh + ((size_t)(16 * j + r)) * HID + 4 * kq);
      wT[(4*kq+0)*16 + r] = v.x; wT[(4*kq+1)*16 + r] = v.y;
      wT[(4*kq+2)*16 + r] = v.z; wT[(4*kq+3)*16 + r] = v.w;
    }
  } else {
    const int j = blk - 64;
#pragma unroll
    for (int p = 0; p < 8; ++p) {
      int idx = tid + 512 * p;
      int half = idx >> 11;
      int id2 = idx & 2047;
      int r = id2 >> 8, kq = id2 & 255;
      const float* W = (half ? Wh : Wi) + (size_t)HID * HID;
      float4 v = *(const float4*)(W + ((size_t)(8 * j + r)) * HID + 4 * kq);
      int kb = half * 1024 + 4 * kq;
      wT[(kb+0)*8 + r] = v.x; wT[(kb+1)*8 + r] = v.y;
      wT[(kb+2)*8 + r] = v.z; wT[(kb+3)*8 + r] = v.w;
    }
    if (tid < 8) bias[tid] = bi[HID + 8 * j + tid] + bh[HID + 8 * j + tid];
  }
  __syncthreads();

  // staging: lane reads 16B at src + (tid&15)*4096B + (tid>>4)*16B (+p*512B)
  const int sb  = tid & 15;
  const int skq = tid >> 4;
  auto hbase = [&](const float* src) {
    return (const float*)((const char*)src + sb * 4096 + skq * 16);
  };
  auto stage_write = [&](const f32x4* d) {
#pragma unroll
    for (int p = 0; p < 8; ++p) {
      int kq = skq + 32 * p;
#pragma unroll
      for (int c = 0; c < 4; ++c) hT[(4*kq+c)*16 + sb] = d[p][c];
    }
  };

  for (int u = 0; u <= SEQ; ++u) {
    if (isL0) {
      if (u < SEQ) {
        f32x4 r0[8];
        LOAD8(r0, hbase(h0g + ((u - 1) & 1) * (BATCH * HID)));
        WAIT8(r0);
        stage_write(r0);
        __syncthreads();
        const int bq = tid & 3, rq = (tid >> 2) & 3, ks = tid >> 4;  // ks 0..31
        float acc[4][4] = {{0.f}};
#pragma unroll 4
        for (int i = 0; i < 32; ++i) {
          int k = ks + 32 * i;
          float4 hv = *(const float4*)&hT[k * 16 + 4 * bq];
          float4 wv = *(const float4*)&wT[k * 16 + 4 * rq];
          float hb[4] = {hv.x, hv.y, hv.z, hv.w};
          float wr[4] = {wv.x, wv.y, wv.z, wv.w};
#pragma unroll
          for (int b_ = 0; b_ < 4; ++b_)
#pragma unroll
            for (int rj = 0; rj < 4; ++rj)
              acc[b_][rj] = fmaf(hb[b_], wr[rj], acc[b_][rj]);
        }
#pragma unroll
        for (int b_ = 0; b_ < 4; ++b_)
#pragma unroll
          for (int rj = 0; rj < 4; ++rj) {
            float v = acc[b_][rj];
            v += __shfl_xor(v, 16); v += __shfl_xor(v, 32);
            acc[b_][rj] = v;
          }
        const int w = tid >> 6;
        if ((tid & 63) < 16) {
#pragma unroll
          for (int b_ = 0; b_ < 4; ++b_)
#pragma unroll
            for (int rj = 0; rj < 4; ++rj)
              part[w * 256 + (4*bq + b_) * 16 + 4*rq + rj] = acc[b_][rj];
        }
        __syncthreads();
        if (tid < 256) {
          int b = tid >> 4, r = tid & 15;
          float s = 0.f;
#pragma unroll
          for (int w2 = 0; w2 < 8; ++w2) s += part[w2 * 256 + b * 16 + r];
          int R = 16 * blk + r;
          s += pre0[((size_t)u * BATCH + b) * HID + R];
          st_coherent(h0g + (u & 1) * (BATCH * HID) + (size_t)b * HID + R, tanhf(s));
        }
      }
    } else {
      if (u >= 1) {
        const int t = u - 1;
        const int bq = tid & 3, rq = (tid >> 2) & 1, ks = tid >> 3;  // ks 0..63
        f32x4 r0[8], r1[8];
        LOAD8(r0, hbase(h0g + (t & 1) * (BATCH * HID)));
        LOAD8(r1, hbase(h1g + ((t - 1) & 1) * (BATCH * HID)));
        WAIT16(r0, r1);
        stage_write(r0);
        __syncthreads();
        float acc[4][4] = {{0.f}};
        // phase A: Wi1 . h0[t]
#pragma unroll 4
        for (int i = 0; i < 16; ++i) {
          int k = ks + 64 * i;
          float4 hv = *(const float4*)&hT[k * 16 + 4 * bq];
          float4 wv = *(const float4*)&wT[k * 8 + 4 * rq];
          float hb[4] = {hv.x, hv.y, hv.z, hv.w};
          float wr[4] = {wv.x, wv.y, wv.z, wv.w};
#pragma unroll
          for (int b_ = 0; b_ < 4; ++b_)
#pragma unroll
            for (int rj = 0; rj < 4; ++rj)
              acc[b_][rj] = fmaf(hb[b_], wr[rj], acc[b_][rj]);
        }
        __syncthreads();   // done reading hT
        stage_write(r1);
        __syncthreads();
        // phase B: Wh1 . h1[t-1]
#pragma unroll 4
        for (int i = 0; i < 16; ++i) {
          int k = ks + 64 * i;
          float4 hv = *(const float4*)&hT[k * 16 + 4 * bq];
          float4 wv = *(const float4*)&wT[(1024 + k) * 8 + 4 * rq];
          float hb[4] = {hv.x, hv.y, hv.z, hv.w};
          float wr[4] = {wv.x, wv.y, wv.z, wv.w};
#pragma unroll
          for (int b_ = 0; b_ < 4; ++b_)
#pragma unroll
            for (int rj = 0; rj < 4; ++rj)
              acc[b_][rj] = fmaf(hb[b_], wr[rj], acc[b_][rj]);
        }
#pragma unroll
        for (int b_ = 0; b_ < 4; ++b_)
#pragma unroll
          for (int rj = 0; rj < 4; ++rj) {
            float v = acc[b_][rj];
            v += __shfl_xor(v, 8); v += __shfl_xor(v, 16); v += __shfl_xor(v, 32);
            acc[b_][rj] = v;
          }
        const int w = tid >> 6;
        if ((tid & 63) < 8) {
#pragma unroll
          for (int b_ = 0; b_ < 4; ++b_)
#pragma unroll
            for (int rj = 0; rj < 4; ++rj)
              part[w * 128 + (4*bq + b_) * 8 + 4*rq + rj] = acc[b_][rj];
        }
        __syncthreads();
        if (tid < 128) {
          int b = tid >> 3, r = tid & 7;
          float s = bias[r];
#pragma unroll
          for (int w2 = 0; w2 < 8; ++w2) s += part[w2 * 128 + b * 8 + r];
          int R = 8 * (blk - 64) + r;
          float v = tanhf(s);
          tops[((size_t)t * BATCH + b) * HID + R] = v;   // read after kernel end
          st_coherent(h1g + (t & 1) * (BATCH * HID) + (size_t)b * HID + R, v);
        }
      }
    }

    if (u == SEQ) break;   // last tick: nothing to publish

    // ---- relaxed barrier: vmcnt-drain, add, spin (no cache maintenance) ----
    asm volatile("s_waitcnt vmcnt(0)" ::: "memory");
    __syncthreads();
    if (tid == 0) {
      __hip_atomic_fetch_add(bar, 1, __ATOMIC_RELAXED, __HIP_MEMORY_SCOPE_AGENT);
      const int target = NBLK * (u + 1);
      while (__hip_atomic_load(bar, __ATOMIC_RELAXED, __HIP_MEMORY_SCOPE_AGENT) < target)
        __builtin_amdgcn_s_sleep(2);
    }
    __syncthreads();
  }
}

// ---------------------------------------------------------------------------
// logits = tops . Wo^T + bo via split-bf16 MFMA (unchanged, passed r3-r5).
// ---------------------------------------------------------------------------
__global__ __launch_bounds__(512, 1) void proj_mfma(
    const float* __restrict__ tops, const float* __restrict__ Wo,
    const float* __restrict__ bo, float* __restrict__ out)
{
  __shared__ ushort Ahi[256 * 64];
  __shared__ ushort Alo[256 * 64];
  __shared__ ushort Bs [256 * 64];
  const int tid  = threadIdx.x;
  const int m0   = blockIdx.x * 256;
  const int n0   = blockIdx.y * 256;
  const int lane = tid & 63, wv = tid >> 6;
  const int wm   = wv & 3, wn = wv >> 2;
  const int bconst = blockIdx.x;

  f32x4 acc[4][8];
#pragma unroll
  for (int i = 0; i < 4; ++i)
#pragma unroll
    for (int j = 0; j < 8; ++j) acc[i][j] = (f32x4)0.f;

  const int sr = tid >> 4;
  const int sk = (tid & 15) * 4;

  for (int kt = 0; kt < HID; kt += 64) {
    __syncthreads();
#pragma unroll
    for (int p = 0; p < 8; ++p) {
      int r = sr + 32 * p;
      float4 v = *(const float4*)(tops + ((size_t)r * BATCH + bconst) * HID + kt + sk);
      float f[4] = {v.x, v.y, v.z, v.w};
      ushort hi[4], lo[4];
#pragma unroll
      for (int c = 0; c < 4; ++c) {
        hi[c] = f2bf(f[c]);
        lo[c] = f2bf(f[c] - bf2f(hi[c]));
      }
      uint off = (uint)(r * 128 + sk * 2) ^ (uint)((r & 7) << 4);
      *(ushort4*)((char*)Ahi + off) = make_ushort4(hi[0], hi[1], hi[2], hi[3]);
      *(ushort4*)((char*)Alo + off) = make_ushort4(lo[0], lo[1], lo[2], lo[3]);
    }
#pragma unroll
    for (int p = 0; p < 8; ++p) {
      int r = sr + 32 * p;
      float4 v = *(const float4*)(Wo + (size_t)(n0 + r) * HID + kt + sk);
      uint off = (uint)(r * 128 + sk * 2) ^ (uint)((r & 7) << 4);
      *(ushort4*)((char*)Bs + off) =
          make_ushort4(f2bf(v.x), f2bf(v.y), f2bf(v.z), f2bf(v.w));
    }
    __syncthreads();

    const int fr = lane & 15, kg = lane >> 4;
#pragma unroll
    for (int kk = 0; kk < 2; ++kk) {
      short8 bf[8], ah[4], al[4];
#pragma unroll
      for (int nf = 0; nf < 8; ++nf) {
        int row = wn * 128 + nf * 16 + fr;
        uint off = (uint)(row * 128 + kk * 64 + kg * 16) ^ (uint)((row & 7) << 4);
        bf[nf] = *(const short8*)((const char*)Bs + off);
      }
#pragma unroll
      for (int mf = 0; mf < 4; ++mf) {
        int row = wm * 64 + mf * 16 + fr;
        uint off = (uint)(row * 128 + kk * 64 + kg * 16) ^ (uint)((row & 7) << 4);
        ah[mf] = *(const short8*)((const char*)Ahi + off);
        al[mf] = *(const short8*)((const char*)Alo + off);
      }
#pragma unroll
      for (int mf = 0; mf < 4; ++mf)
#pragma unroll
        for (int nf = 0; nf < 8; ++nf) {
          acc[mf][nf] = __builtin_amdgcn_mfma_f32_16x16x32_bf16(
              ah[mf], bf[nf], acc[mf][nf], 0, 0, 0);
          acc[mf][nf] = __builtin_amdgcn_mfma_f32_16x16x32_bf16(
              al[mf], bf[nf], acc[mf][nf], 0, 0, 0);
        }
    }
  }

  const int fr = lane & 15, rg = lane >> 4;
#pragma unroll
  for (int mf = 0; mf < 4; ++mf)
#pragma unroll
    for (int nf = 0; nf < 8; ++nf) {
      int n = n0 + wn * 128 + nf * 16 + fr;
      float bb = bo[n];
#pragma unroll
      for (int j = 0; j < 4; ++j) {
        int m = m0 + wm * 64 + mf * 16 + rg * 4 + j;
        out[(size_t)m * VOCAB + n] = acc[mf][nf][j] + bb;
      }
    }
}

// hidden[0][b][n] = h0 step 255 (parity 1); hidden[1][b][n] = tops[255]
__global__ void copy_hidden(const float* __restrict__ h0g,
                            const float* __restrict__ tops,
                            float* __restrict__ outh)
{
  int i = blockIdx.x * 256 + threadIdx.x;   // 0..32767
  int l = i >> 14, rem = i & 16383;
  outh[i] = (l == 0) ? h0g[BATCH * HID + rem]
                     : tops[(size_t)(SEQ - 1) * (BATCH * HID) + rem];
}

extern "C" void kernel_launch(void* const* d_in, const int* in_sizes, int n_in,
                              void* d_out, int out_size, void* d_ws, size_t ws_size,
                              hipStream_t stream)
{
  const int*   x     = (const int*)d_in[0];
  const float* embed = (const float*)d_in[1];
  const float* Wi    = (const float*)d_in[2];
  const float* bi    = (const float*)d_in[3];
  const float* Wh    = (const float*)d_in[4];
  const float* bh    = (const float*)d_in[5];
  const float* Wo    = (const float*)d_in[6];
  const float* bo    = (const float*)d_in[7];
  float* out = (float*)d_out;

  char* ws = (char*)d_ws;
  float* pre0 = (float*)(ws);                          // 16 MiB [t][b][n]
  float* tops = (float*)(ws + (16u << 20));            // 16 MiB [t][b][n]
  float* h0g  = (float*)(ws + (32u << 20));            // 2 x 64 KiB
  float* h1g  = (float*)(ws + (32u << 20) + 131072);   // 2 x 64 KiB
  int*   bar  = (int*)  (ws + (32u << 20) + 262144);   // barrier counter

  // zero h parities + barrier counter (deterministic across replays)
  hipMemsetAsync(h0g, 0, 262144 + 4096, stream);

  pre0_gemm<<<dim3(8, 32), dim3(256), 0, stream>>>(x, embed, Wi, bi, bh, pre0);

  void* args[] = { (void*)&Wi, (void*)&Wh, (void*)&bi, (void*)&bh,
                   (void*)&pre0, (void*)&h0g, (void*)&h1g, (void*)&tops,
                   (void*)&bar };
  hipLaunchCooperativeKernel((void*)rnn_scan, dim3(NBLK), dim3(512), args, 0, stream);

  proj_mfma<<<dim3(16, 125), dim3(512), 0, stream>>>(tops, Wo, bo, out);

  copy_hidden<<<dim3(128), dim3(256), 0, stream>>>(
      h0g, tops, out + (size_t)BATCH * SEQ * VOCAB);
}

// Round 8
// 3436.927 us; speedup vs baseline: 1.9076x; 1.2296x over previous
//
#include <hip/hip_runtime.h>
#include <cmath>
#include <cstdint>

#define VOCAB 32000
#define HID   1024
#define BATCH 16
#define SEQ   256
#define NBLK  192

typedef __attribute__((ext_vector_type(8))) short short8;
typedef __attribute__((ext_vector_type(4))) float f32x4;

__device__ __forceinline__ ushort f2bf(float f) {  // RNE fp32 -> bf16 bits
  uint u = __builtin_bit_cast(uint, f);
  return (ushort)((u + 0x7FFFu + ((u >> 16) & 1u)) >> 16);
}
__device__ __forceinline__ float bf2f(ushort h) {
  return __builtin_bit_cast(float, (uint)h << 16);
}

// ---- MALL-coherent vector load/store (sc0 sc1), no cache maintenance ------
#define LOAD8(d, base)                                                        \
  asm volatile(                                                               \
    "global_load_dwordx4 %0, %8, off sc0 sc1\n\t"                             \
    "global_load_dwordx4 %1, %8, off offset:512 sc0 sc1\n\t"                  \
    "global_load_dwordx4 %2, %8, off offset:1024 sc0 sc1\n\t"                 \
    "global_load_dwordx4 %3, %8, off offset:1536 sc0 sc1\n\t"                 \
    "global_load_dwordx4 %4, %8, off offset:2048 sc0 sc1\n\t"                 \
    "global_load_dwordx4 %5, %8, off offset:2560 sc0 sc1\n\t"                 \
    "global_load_dwordx4 %6, %8, off offset:3072 sc0 sc1\n\t"                 \
    "global_load_dwordx4 %7, %8, off offset:3584 sc0 sc1"                     \
    : "=&v"(d[0]), "=&v"(d[1]), "=&v"(d[2]), "=&v"(d[3]),                     \
      "=&v"(d[4]), "=&v"(d[5]), "=&v"(d[6]), "=&v"(d[7])                      \
    : "v"(base) : "memory")

#define WAIT8(d)                                                              \
  asm volatile("s_waitcnt vmcnt(0)"                                           \
    : "+v"(d[0]), "+v"(d[1]), "+v"(d[2]), "+v"(d[3]),                         \
      "+v"(d[4]), "+v"(d[5]), "+v"(d[6]), "+v"(d[7]) :: "memory")

#define WAIT16(a, b)                                                          \
  asm volatile("s_waitcnt vmcnt(0)"                                           \
    : "+v"(a[0]), "+v"(a[1]), "+v"(a[2]), "+v"(a[3]),                         \
      "+v"(a[4]), "+v"(a[5]), "+v"(a[6]), "+v"(a[7]),                         \
      "+v"(b[0]), "+v"(b[1]), "+v"(b[2]), "+v"(b[3]),                         \
      "+v"(b[4]), "+v"(b[5]), "+v"(b[6]), "+v"(b[7]) :: "memory")

__device__ __forceinline__ void st_coherent(float* p, float v) {
  asm volatile("global_store_dword %0, %1, off sc0 sc1" :: "v"(p), "v"(v) : "memory");
}

// ---------------------------------------------------------------------------
// pre0[t][b][n] = embed[x[b][t]] . Wi0[n] + bi0[n] + bh0[n]   (unchanged)
// ---------------------------------------------------------------------------
__global__ __launch_bounds__(256) void pre0_gemm(
    const int* __restrict__ x, const float* __restrict__ embed,
    const float* __restrict__ Wi0, const float* __restrict__ bi0,
    const float* __restrict__ bh0, float* __restrict__ pre)
{
  __shared__ float As[32][132];
  __shared__ float Bs[32][132];
  const int tid  = threadIdx.x;
  const int n0   = blockIdx.x * 128;
  const int m0   = blockIdx.y * 128;
  const int lrow = tid >> 3, lkq = tid & 7;
  const int ty   = tid >> 4, tx  = tid & 15;

  const float* arow[4];
#pragma unroll
  for (int q = 0; q < 4; ++q) {
    int m = m0 + lrow + 32 * q;
    int t = m >> 4, b = m & 15;
    arow[q] = embed + (size_t)x[b * SEQ + t] * HID;
  }
  const float* brow = Wi0 + (size_t)(n0 + lrow) * HID;

  float acc[8][8];
#pragma unroll
  for (int i = 0; i < 8; ++i)
#pragma unroll
    for (int j = 0; j < 8; ++j) acc[i][j] = 0.f;

  for (int kt = 0; kt < HID; kt += 32) {
    float4 av[4], bv[4];
#pragma unroll
    for (int q = 0; q < 4; ++q) {
      av[q] = *(const float4*)(arow[q] + kt + lkq * 4);
      bv[q] = *(const float4*)(brow + (size_t)(32 * q) * HID + kt + lkq * 4);
    }
    __syncthreads();
#pragma unroll
    for (int q = 0; q < 4; ++q) {
      int r = lrow + 32 * q;
      As[lkq*4+0][r] = av[q].x; As[lkq*4+1][r] = av[q].y;
      As[lkq*4+2][r] = av[q].z; As[lkq*4+3][r] = av[q].w;
      Bs[lkq*4+0][r] = bv[q].x; Bs[lkq*4+1][r] = bv[q].y;
      Bs[lkq*4+2][r] = bv[q].z; Bs[lkq*4+3][r] = bv[q].w;
    }
    __syncthreads();
#pragma unroll
    for (int kk = 0; kk < 32; ++kk) {
      float4 a0 = *(const float4*)&As[kk][ty * 8];
      float4 a1 = *(const float4*)&As[kk][ty * 8 + 4];
      float4 b0 = *(const float4*)&Bs[kk][tx * 8];
      float4 b1 = *(const float4*)&Bs[kk][tx * 8 + 4];
      float a[8] = {a0.x,a0.y,a0.z,a0.w,a1.x,a1.y,a1.z,a1.w};
      float b[8] = {b0.x,b0.y,b0.z,b0.w,b1.x,b1.y,b1.z,b1.w};
#pragma unroll
      for (int i = 0; i < 8; ++i)
#pragma unroll
        for (int j = 0; j < 8; ++j) acc[i][j] = fmaf(a[i], b[j], acc[i][j]);
    }
  }

#pragma unroll
  for (int i = 0; i < 8; ++i) {
    int m = m0 + ty * 8 + i;
    float* o = pre + (size_t)m * HID + n0 + tx * 8;
#pragma unroll
    for (int j = 0; j < 8; ++j) {
      int n = n0 + tx * 8 + j;
      o[j] = acc[i][j] + bi0[n] + bh0[n];
    }
  }
}

// ---------------------------------------------------------------------------
// Fused skewed cooperative scan. Relaxed barrier with 8 SPREAD arrival
// counters (128B apart) to kill same-address RMW serialization; spinner
// sums the 8 lines against the monotone target. h via sc0sc1 vector ops.
//  Blocks 0..63  (L0): 16 rows Wh0 in LDS; tick u<256 computes h0[u].
//  Blocks 64..191 (L1): 8 rows [Wi1|Wh1]; tick u>=1 computes h1[u-1].
// ---------------------------------------------------------------------------
__global__ __launch_bounds__(512) void rnn_scan(
    const float* __restrict__ Wi, const float* __restrict__ Wh,
    const float* __restrict__ bi, const float* __restrict__ bh,
    const float* __restrict__ pre0, float* __restrict__ h0g,
    float* __restrict__ h1g, float* __restrict__ tops,
    int* __restrict__ bar)
{
  __shared__ float wT[16 * 1024];   // L0: [k][16]; L1: [k2][8], k2<2048
  __shared__ float hT[1024 * 16];   // [k][16] staged h
  __shared__ float part[2048];
  __shared__ float bias[8];

  const int tid = threadIdx.x;
  const int blk = blockIdx.x;
  const bool isL0 = (blk < 64);

  if (isL0) {
    const int j = blk;
#pragma unroll
    for (int p = 0; p < 8; ++p) {
      int idx = tid + 512 * p;
      int r = idx >> 8, kq = idx & 255;
      float4 v = *(const float4*)(Wh + ((size_t)(16 * j + r)) * HID + 4 * kq);
      wT[(4*kq+0)*16 + r] = v.x; wT[(4*kq+1)*16 + r] = v.y;
      wT[(4*kq+2)*16 + r] = v.z; wT[(4*kq+3)*16 + r] = v.w;
    }
  } else {
    const int j = blk - 64;
#pragma unroll
    for (int p = 0; p < 8; ++p) {
      int idx = tid + 512 * p;
      int half = idx >> 11;
      int id2 = idx & 2047;
      int r = id2 >> 8, kq = id2 & 255;
      const float* W = (half ? Wh : Wi) + (size_t)HID * HID;
      float4 v = *(const float4*)(W + ((size_t)(8 * j + r)) * HID + 4 * kq);
      int kb = half * 1024 + 4 * kq;
      wT[(kb+0)*8 + r] = v.x; wT[(kb+1)*8 + r] = v.y;
      wT[(kb+2)*8 + r] = v.z; wT[(kb+3)*8 + r] = v.w;
    }
    if (tid < 8) bias[tid] = bi[HID + 8 * j + tid] + bh[HID + 8 * j + tid];
  }
  __syncthreads();

  // staging: lane reads 16B at src + (tid&15)*4096B + (tid>>4)*16B (+p*512B)
  const int sb  = tid & 15;
  const int skq = tid >> 4;
  auto hbase = [&](const float* src) {
    return (const float*)((const char*)src + sb * 4096 + skq * 16);
  };
  auto stage_write = [&](const f32x4* d) {
#pragma unroll
    for (int p = 0; p < 8; ++p) {
      int kq = skq + 32 * p;
#pragma unroll
      for (int c = 0; c < 4; ++c) hT[(4*kq+c)*16 + sb] = d[p][c];
    }
  };

  for (int u = 0; u <= SEQ; ++u) {
    if (isL0) {
      if (u < SEQ) {
        f32x4 r0[8];
        LOAD8(r0, hbase(h0g + ((u - 1) & 1) * (BATCH * HID)));
        WAIT8(r0);
        stage_write(r0);
        __syncthreads();
        const int bq = tid & 3, rq = (tid >> 2) & 3, ks = tid >> 4;  // ks 0..31
        float acc[4][4] = {{0.f}};
#pragma unroll 4
        for (int i = 0; i < 32; ++i) {
          int k = ks + 32 * i;
          float4 hv = *(const float4*)&hT[k * 16 + 4 * bq];
          float4 wv = *(const float4*)&wT[k * 16 + 4 * rq];
          float hb[4] = {hv.x, hv.y, hv.z, hv.w};
          float wr[4] = {wv.x, wv.y, wv.z, wv.w};
#pragma unroll
          for (int b_ = 0; b_ < 4; ++b_)
#pragma unroll
            for (int rj = 0; rj < 4; ++rj)
              acc[b_][rj] = fmaf(hb[b_], wr[rj], acc[b_][rj]);
        }
#pragma unroll
        for (int b_ = 0; b_ < 4; ++b_)
#pragma unroll
          for (int rj = 0; rj < 4; ++rj) {
            float v = acc[b_][rj];
            v += __shfl_xor(v, 16); v += __shfl_xor(v, 32);
            acc[b_][rj] = v;
          }
        const int w = tid >> 6;
        if ((tid & 63) < 16) {
#pragma unroll
          for (int b_ = 0; b_ < 4; ++b_)
#pragma unroll
            for (int rj = 0; rj < 4; ++rj)
              part[w * 256 + (4*bq + b_) * 16 + 4*rq + rj] = acc[b_][rj];
        }
        __syncthreads();
        if (tid < 256) {
          int b = tid >> 4, r = tid & 15;
          float s = 0.f;
#pragma unroll
          for (int w2 = 0; w2 < 8; ++w2) s += part[w2 * 256 + b * 16 + r];
          int R = 16 * blk + r;
          s += pre0[((size_t)u * BATCH + b) * HID + R];
          st_coherent(h0g + (u & 1) * (BATCH * HID) + (size_t)b * HID + R, tanhf(s));
        }
      }
    } else {
      if (u >= 1) {
        const int t = u - 1;
        const int bq = tid & 3, rq = (tid >> 2) & 1, ks = tid >> 3;  // ks 0..63
        f32x4 r0[8], r1[8];
        LOAD8(r0, hbase(h0g + (t & 1) * (BATCH * HID)));
        LOAD8(r1, hbase(h1g + ((t - 1) & 1) * (BATCH * HID)));
        WAIT16(r0, r1);
        stage_write(r0);
        __syncthreads();
        float acc[4][4] = {{0.f}};
        // phase A: Wi1 . h0[t]
#pragma unroll 4
        for (int i = 0; i < 16; ++i) {
          int k = ks + 64 * i;
          float4 hv = *(const float4*)&hT[k * 16 + 4 * bq];
          float4 wv = *(const float4*)&wT[k * 8 + 4 * rq];
          float hb[4] = {hv.x, hv.y, hv.z, hv.w};
          float wr[4] = {wv.x, wv.y, wv.z, wv.w};
#pragma unroll
          for (int b_ = 0; b_ < 4; ++b_)
#pragma unroll
            for (int rj = 0; rj < 4; ++rj)
              acc[b_][rj] = fmaf(hb[b_], wr[rj], acc[b_][rj]);
        }
        __syncthreads();   // done reading hT
        stage_write(r1);
        __syncthreads();
        // phase B: Wh1 . h1[t-1]
#pragma unroll 4
        for (int i = 0; i < 16; ++i) {
          int k = ks + 64 * i;
          float4 hv = *(const float4*)&hT[k * 16 + 4 * bq];
          float4 wv = *(const float4*)&wT[(1024 + k) * 8 + 4 * rq];
          float hb[4] = {hv.x, hv.y, hv.z, hv.w};
          float wr[4] = {wv.x, wv.y, wv.z, wv.w};
#pragma unroll
          for (int b_ = 0; b_ < 4; ++b_)
#pragma unroll
            for (int rj = 0; rj < 4; ++rj)
              acc[b_][rj] = fmaf(hb[b_], wr[rj], acc[b_][rj]);
        }
#pragma unroll
        for (int b_ = 0; b_ < 4; ++b_)
#pragma unroll
          for (int rj = 0; rj < 4; ++rj) {
            float v = acc[b_][rj];
            v += __shfl_xor(v, 8); v += __shfl_xor(v, 16); v += __shfl_xor(v, 32);
            acc[b_][rj] = v;
          }
        const int w = tid >> 6;
        if ((tid & 63) < 8) {
#pragma unroll
          for (int b_ = 0; b_ < 4; ++b_)
#pragma unroll
            for (int rj = 0; rj < 4; ++rj)
              part[w * 128 + (4*bq + b_) * 8 + 4*rq + rj] = acc[b_][rj];
        }
        __syncthreads();
        if (tid < 128) {
          int b = tid >> 3, r = tid & 7;
          float s = bias[r];
#pragma unroll
          for (int w2 = 0; w2 < 8; ++w2) s += part[w2 * 128 + b * 8 + r];
          int R = 8 * (blk - 64) + r;
          float v = tanhf(s);
          tops[((size_t)t * BATCH + b) * HID + R] = v;   // read after kernel end
          st_coherent(h1g + (t & 1) * (BATCH * HID) + (size_t)b * HID + R, v);
        }
      }
    }

    if (u == SEQ) break;   // last tick: nothing to publish

    // ---- relaxed barrier, 8 spread arrival lines (no same-addr serialize) --
    asm volatile("s_waitcnt vmcnt(0)" ::: "memory");
    __syncthreads();
    if (tid == 0) {
      __hip_atomic_fetch_add(bar + (blk & 7) * 32, 1,
                             __ATOMIC_RELAXED, __HIP_MEMORY_SCOPE_AGENT);
      const int target = NBLK * (u + 1);
      for (;;) {
        int s = 0;
#pragma unroll
        for (int i = 0; i < 8; ++i)
          s += __hip_atomic_load(bar + i * 32,
                                 __ATOMIC_RELAXED, __HIP_MEMORY_SCOPE_AGENT);
        if (s >= target) break;
        __builtin_amdgcn_s_sleep(1);
      }
    }
    __syncthreads();
  }
}

// ---------------------------------------------------------------------------
// logits = tops . Wo^T + bo via split-bf16 MFMA (unchanged, passed r3-r7).
// ---------------------------------------------------------------------------
__global__ __launch_bounds__(512, 1) void proj_mfma(
    const float* __restrict__ tops, const float* __restrict__ Wo,
    const float* __restrict__ bo, float* __restrict__ out)
{
  __shared__ ushort Ahi[256 * 64];
  __shared__ ushort Alo[256 * 64];
  __shared__ ushort Bs [256 * 64];
  const int tid  = threadIdx.x;
  const int m0   = blockIdx.x * 256;
  const int n0   = blockIdx.y * 256;
  const int lane = tid & 63, wv = tid >> 6;
  const int wm   = wv & 3, wn = wv >> 2;
  const int bconst = blockIdx.x;

  f32x4 acc[4][8];
#pragma unroll
  for (int i = 0; i < 4; ++i)
#pragma unroll
    for (int j = 0; j < 8; ++j) acc[i][j] = (f32x4)0.f;

  const int sr = tid >> 4;
  const int sk = (tid & 15) * 4;

  for (int kt = 0; kt < HID; kt += 64) {
    __syncthreads();
#pragma unroll
    for (int p = 0; p < 8; ++p) {
      int r = sr + 32 * p;
      float4 v = *(const float4*)(tops + ((size_t)r * BATCH + bconst) * HID + kt + sk);
      float f[4] = {v.x, v.y, v.z, v.w};
      ushort hi[4], lo[4];
#pragma unroll
      for (int c = 0; c < 4; ++c) {
        hi[c] = f2bf(f[c]);
        lo[c] = f2bf(f[c] - bf2f(hi[c]));
      }
      uint off = (uint)(r * 128 + sk * 2) ^ (uint)((r & 7) << 4);
      *(ushort4*)((char*)Ahi + off) = make_ushort4(hi[0], hi[1], hi[2], hi[3]);
      *(ushort4*)((char*)Alo + off) = make_ushort4(lo[0], lo[1], lo[2], lo[3]);
    }
#pragma unroll
    for (int p = 0; p < 8; ++p) {
      int r = sr + 32 * p;
      float4 v = *(const float4*)(Wo + (size_t)(n0 + r) * HID + kt + sk);
      uint off = (uint)(r * 128 + sk * 2) ^ (uint)((r & 7) << 4);
      *(ushort4*)((char*)Bs + off) =
          make_ushort4(f2bf(v.x), f2bf(v.y), f2bf(v.z), f2bf(v.w));
    }
    __syncthreads();

    const int fr = lane & 15, kg = lane >> 4;
#pragma unroll
    for (int kk = 0; kk < 2; ++kk) {
      short8 bf[8], ah[4], al[4];
#pragma unroll
      for (int nf = 0; nf < 8; ++nf) {
        int row = wn * 128 + nf * 16 + fr;
        uint off = (uint)(row * 128 + kk * 64 + kg * 16) ^ (uint)((row & 7) << 4);
        bf[nf] = *(const short8*)((const char*)Bs + off);
      }
#pragma unroll
      for (int mf = 0; mf < 4; ++mf) {
        int row = wm * 64 + mf * 16 + fr;
        uint off = (uint)(row * 128 + kk * 64 + kg * 16) ^ (uint)((row & 7) << 4);
        ah[mf] = *(const short8*)((const char*)Ahi + off);
        al[mf] = *(const short8*)((const char*)Alo + off);
      }
#pragma unroll
      for (int mf = 0; mf < 4; ++mf)
#pragma unroll
        for (int nf = 0; nf < 8; ++nf) {
          acc[mf][nf] = __builtin_amdgcn_mfma_f32_16x16x32_bf16(
              ah[mf], bf[nf], acc[mf][nf], 0, 0, 0);
          acc[mf][nf] = __builtin_amdgcn_mfma_f32_16x16x32_bf16(
              al[mf], bf[nf], acc[mf][nf], 0, 0, 0);
        }
    }
  }

  const int fr = lane & 15, rg = lane >> 4;
#pragma unroll
  for (int mf = 0; mf < 4; ++mf)
#pragma unroll
    for (int nf = 0; nf < 8; ++nf) {
      int n = n0 + wn * 128 + nf * 16 + fr;
      float bb = bo[n];
#pragma unroll
      for (int j = 0; j < 4; ++j) {
        int m = m0 + wm * 64 + mf * 16 + rg * 4 + j;
        out[(size_t)m * VOCAB + n] = acc[mf][nf][j] + bb;
      }
    }
}

// hidden[0][b][n] = h0 step 255 (parity 1); hidden[1][b][n] = tops[255]
__global__ void copy_hidden(const float* __restrict__ h0g,
                            const float* __restrict__ tops,
                            float* __restrict__ outh)
{
  int i = blockIdx.x * 256 + threadIdx.x;   // 0..32767
  int l = i >> 14, rem = i & 16383;
  outh[i] = (l == 0) ? h0g[BATCH * HID + rem]
                     : tops[(size_t)(SEQ - 1) * (BATCH * HID) + rem];
}

extern "C" void kernel_launch(void* const* d_in, const int* in_sizes, int n_in,
                              void* d_out, int out_size, void* d_ws, size_t ws_size,
                              hipStream_t stream)
{
  const int*   x     = (const int*)d_in[0];
  const float* embed = (const float*)d_in[1];
  const float* Wi    = (const float*)d_in[2];
  const float* bi    = (const float*)d_in[3];
  const float* Wh    = (const float*)d_in[4];
  const float* bh    = (const float*)d_in[5];
  const float* Wo    = (const float*)d_in[6];
  const float* bo    = (const float*)d_in[7];
  float* out = (float*)d_out;

  char* ws = (char*)d_ws;
  float* pre0 = (float*)(ws);                          // 16 MiB [t][b][n]
  float* tops = (float*)(ws + (16u << 20));            // 16 MiB [t][b][n]
  float* h0g  = (float*)(ws + (32u << 20));            // 2 x 64 KiB
  float* h1g  = (float*)(ws + (32u << 20) + 131072);   // 2 x 64 KiB
  int*   bar  = (int*)  (ws + (32u << 20) + 262144);   // 8 spread counters

  // zero h parities + barrier counters (deterministic across replays)
  hipMemsetAsync(h0g, 0, 262144 + 4096, stream);

  pre0_gemm<<<dim3(8, 32), dim3(256), 0, stream>>>(x, embed, Wi, bi, bh, pre0);

  void* args[] = { (void*)&Wi, (void*)&Wh, (void*)&bi, (void*)&bh,
                   (void*)&pre0, (void*)&h0g, (void*)&h1g, (void*)&tops,
                   (void*)&bar };
  hipLaunchCooperativeKernel((void*)rnn_scan, dim3(NBLK), dim3(512), args, 0, stream);

  proj_mfma<<<dim3(16, 125), dim3(512), 0, stream>>>(tops, Wo, bo, out);

  copy_hidden<<<dim3(128), dim3(256), 0, stream>>>(
      h0g, tops, out + (size_t)BATCH * SEQ * VOCAB);
}

// Round 9
// 3178.165 us; speedup vs baseline: 2.0629x; 1.0814x over previous
//
#include <hip/hip_runtime.h>
#include <cmath>
#include <cstdint>

#define VOCAB 32000
#define HID   1024
#define BATCH 16
#define SEQ   256
#define NL0   64
#define NL1   128
#define NBLK  (NL0 + NL1)
#define BH    (BATCH * HID)

typedef __attribute__((ext_vector_type(8))) short short8;
typedef __attribute__((ext_vector_type(4))) float f32x4;

__device__ __forceinline__ ushort f2bf(float f) {  // RNE fp32 -> bf16 bits
  uint u = __builtin_bit_cast(uint, f);
  return (ushort)((u + 0x7FFFu + ((u >> 16) & 1u)) >> 16);
}
__device__ __forceinline__ float bf2f(ushort h) {
  return __builtin_bit_cast(float, (uint)h << 16);
}

// ---- MALL-coherent vector load/store (sc0 sc1), early-clobber outputs ----
#define LOAD8(d, base)                                                        \
  asm volatile(                                                               \
    "global_load_dwordx4 %0, %8, off sc0 sc1\n\t"                             \
    "global_load_dwordx4 %1, %8, off offset:512 sc0 sc1\n\t"                  \
    "global_load_dwordx4 %2, %8, off offset:1024 sc0 sc1\n\t"                 \
    "global_load_dwordx4 %3, %8, off offset:1536 sc0 sc1\n\t"                 \
    "global_load_dwordx4 %4, %8, off offset:2048 sc0 sc1\n\t"                 \
    "global_load_dwordx4 %5, %8, off offset:2560 sc0 sc1\n\t"                 \
    "global_load_dwordx4 %6, %8, off offset:3072 sc0 sc1\n\t"                 \
    "global_load_dwordx4 %7, %8, off offset:3584 sc0 sc1"                     \
    : "=&v"(d[0]), "=&v"(d[1]), "=&v"(d[2]), "=&v"(d[3]),                     \
      "=&v"(d[4]), "=&v"(d[5]), "=&v"(d[6]), "=&v"(d[7])                      \
    : "v"(base) : "memory")

#define WAIT8(d)                                                              \
  asm volatile("s_waitcnt vmcnt(0)"                                           \
    : "+v"(d[0]), "+v"(d[1]), "+v"(d[2]), "+v"(d[3]),                         \
      "+v"(d[4]), "+v"(d[5]), "+v"(d[6]), "+v"(d[7]) :: "memory")

#define WAIT16(a, b)                                                          \
  asm volatile("s_waitcnt vmcnt(0)"                                           \
    : "+v"(a[0]), "+v"(a[1]), "+v"(a[2]), "+v"(a[3]),                         \
      "+v"(a[4]), "+v"(a[5]), "+v"(a[6]), "+v"(a[7]),                         \
      "+v"(b[0]), "+v"(b[1]), "+v"(b[2]), "+v"(b[3]),                         \
      "+v"(b[4]), "+v"(b[5]), "+v"(b[6]), "+v"(b[7]) :: "memory")

__device__ __forceinline__ void st_coherent(float* p, float v) {
  asm volatile("global_store_dword %0, %1, off sc0 sc1" :: "v"(p), "v"(v) : "memory");
}
__device__ __forceinline__ int ld_rlx(const int* p) {
  return __hip_atomic_load(p, __ATOMIC_RELAXED, __HIP_MEMORY_SCOPE_AGENT);
}
__device__ __forceinline__ void st_rlx(int* p, int v) {
  __hip_atomic_store(p, v, __ATOMIC_RELAXED, __HIP_MEMORY_SCOPE_AGENT);
}

// ---------------------------------------------------------------------------
// pre0[t][b][n] = embed[x[b][t]] . Wi0[n] + bi0[n] + bh0[n]   (unchanged)
// ---------------------------------------------------------------------------
__global__ __launch_bounds__(256) void pre0_gemm(
    const int* __restrict__ x, const float* __restrict__ embed,
    const float* __restrict__ Wi0, const float* __restrict__ bi0,
    const float* __restrict__ bh0, float* __restrict__ pre)
{
  __shared__ float As[32][132];
  __shared__ float Bs[32][132];
  const int tid  = threadIdx.x;
  const int n0   = blockIdx.x * 128;
  const int m0   = blockIdx.y * 128;
  const int lrow = tid >> 3, lkq = tid & 7;
  const int ty   = tid >> 4, tx  = tid & 15;

  const float* arow[4];
#pragma unroll
  for (int q = 0; q < 4; ++q) {
    int m = m0 + lrow + 32 * q;
    int t = m >> 4, b = m & 15;
    arow[q] = embed + (size_t)x[b * SEQ + t] * HID;
  }
  const float* brow = Wi0 + (size_t)(n0 + lrow) * HID;

  float acc[8][8];
#pragma unroll
  for (int i = 0; i < 8; ++i)
#pragma unroll
    for (int j = 0; j < 8; ++j) acc[i][j] = 0.f;

  for (int kt = 0; kt < HID; kt += 32) {
    float4 av[4], bv[4];
#pragma unroll
    for (int q = 0; q < 4; ++q) {
      av[q] = *(const float4*)(arow[q] + kt + lkq * 4);
      bv[q] = *(const float4*)(brow + (size_t)(32 * q) * HID + kt + lkq * 4);
    }
    __syncthreads();
#pragma unroll
    for (int q = 0; q < 4; ++q) {
      int r = lrow + 32 * q;
      As[lkq*4+0][r] = av[q].x; As[lkq*4+1][r] = av[q].y;
      As[lkq*4+2][r] = av[q].z; As[lkq*4+3][r] = av[q].w;
      Bs[lkq*4+0][r] = bv[q].x; Bs[lkq*4+1][r] = bv[q].y;
      Bs[lkq*4+2][r] = bv[q].z; Bs[lkq*4+3][r] = bv[q].w;
    }
    __syncthreads();
#pragma unroll
    for (int kk = 0; kk < 32; ++kk) {
      float4 a0 = *(const float4*)&As[kk][ty * 8];
      float4 a1 = *(const float4*)&As[kk][ty * 8 + 4];
      float4 b0 = *(const float4*)&Bs[kk][tx * 8];
      float4 b1 = *(const float4*)&Bs[kk][tx * 8 + 4];
      float a[8] = {a0.x,a0.y,a0.z,a0.w,a1.x,a1.y,a1.z,a1.w};
      float b[8] = {b0.x,b0.y,b0.z,b0.w,b1.x,b1.y,b1.z,b1.w};
#pragma unroll
      for (int i = 0; i < 8; ++i)
#pragma unroll
        for (int j = 0; j < 8; ++j) acc[i][j] = fmaf(a[i], b[j], acc[i][j]);
    }
  }

#pragma unroll
  for (int i = 0; i < 8; ++i) {
    int m = m0 + ty * 8 + i;
    float* o = pre + (size_t)m * HID + n0 + tx * 8;
#pragma unroll
    for (int j = 0; j < 8; ++j) {
      int n = n0 + tx * 8 + j;
      o[j] = acc[i][j] + bi0[n] + bh0[n];
    }
  }
}

// ---------------------------------------------------------------------------
// Decoupled 2-cohort scan with master/go-flag sync.
//  arrivals: lines 0..3 (L0, blk&3), 4..7 (L1, blk&3). go0=line 8, go1=line 9.
//  L0 (blocks 0..63, 16 rows Wh0): tick u writes h0ring slot u&7.
//     gates: go0 >= u ; go1 >= u-7 (ring safety).
//  L1 (blocks 64..191, 8 rows [Wi1|Wh1]): step t writes h1[t&1], tops[t].
//     gates: go0 >= t+1 ; go1 >= t.
//  Masters: blk 0 publishes go0, blk 64 publishes go1 (sum own arrival lines).
// Ordering: h stores are sc0sc1 (visible at MALL), drained (vmcnt0+barrier)
// before the arrival RMW; consumers load h with sc0sc1 after observing go.
// ---------------------------------------------------------------------------
__global__ __launch_bounds__(512) void rnn_scan(
    const float* __restrict__ Wi, const float* __restrict__ Wh,
    const float* __restrict__ bi, const float* __restrict__ bh,
    const float* __restrict__ pre0, float* __restrict__ h0ring,
    float* __restrict__ h1g, float* __restrict__ tops,
    int* __restrict__ bar)
{
  __shared__ float wT[16 * 1024];   // L0: [k][16]; L1: [k2][8], k2<2048
  __shared__ float hT[1024 * 16];   // [k][16] staged h
  __shared__ float part[2048];
  __shared__ float bias[8];

  const int tid = threadIdx.x;
  const int blk = blockIdx.x;
  const bool isL0 = (blk < NL0);
  int* go0 = bar + 8 * 32;
  int* go1 = bar + 9 * 32;

  if (isL0) {
    const int j = blk;
#pragma unroll
    for (int p = 0; p < 8; ++p) {
      int idx = tid + 512 * p;
      int r = idx >> 8, kq = idx & 255;
      float4 v = *(const float4*)(Wh + ((size_t)(16 * j + r)) * HID + 4 * kq);
      wT[(4*kq+0)*16 + r] = v.x; wT[(4*kq+1)*16 + r] = v.y;
      wT[(4*kq+2)*16 + r] = v.z; wT[(4*kq+3)*16 + r] = v.w;
    }
  } else {
    const int j = blk - NL0;
#pragma unroll
    for (int p = 0; p < 8; ++p) {
      int idx = tid + 512 * p;
      int half = idx >> 11;
      int id2 = idx & 2047;
      int r = id2 >> 8, kq = id2 & 255;
      const float* W = (half ? Wh : Wi) + (size_t)HID * HID;
      float4 v = *(const float4*)(W + ((size_t)(8 * j + r)) * HID + 4 * kq);
      int kb = half * 1024 + 4 * kq;
      wT[(kb+0)*8 + r] = v.x; wT[(kb+1)*8 + r] = v.y;
      wT[(kb+2)*8 + r] = v.z; wT[(kb+3)*8 + r] = v.w;
    }
    if (tid < 8) bias[tid] = bi[HID + 8 * j + tid] + bh[HID + 8 * j + tid];
  }
  __syncthreads();

  const int sb  = tid & 15;
  const int skq = tid >> 4;
  auto hbase = [&](const float* src) {
    return (const float*)((const char*)src + sb * 4096 + skq * 16);
  };
  auto stage_write = [&](const f32x4* d) {
#pragma unroll
    for (int p = 0; p < 8; ++p) {
      int kq = skq + 32 * p;
#pragma unroll
      for (int c = 0; c < 4; ++c) hT[(4*kq+c)*16 + sb] = d[p][c];
    }
  };

  if (isL0) {
    // =============================== L0 ===================================
    const int bq = tid & 3, rq = (tid >> 2) & 3, ks = tid >> 4;  // ks 0..31
    for (int u = 0; u < SEQ; ++u) {
      // prefetch own pre0 element (gate-independent, hides L2/HBM latency)
      float myPre = 0.f;
      if (tid < 256)
        myPre = pre0[((size_t)u * BATCH + (tid >> 4)) * HID + 16 * blk + (tid & 15)];

      if (tid == 0) {
        while (ld_rlx(go0) < u) __builtin_amdgcn_s_sleep(1);
        const int need = u - 7;
        if (need > 0)
          while (ld_rlx(go1) < need) __builtin_amdgcn_s_sleep(1);
      }
      __syncthreads();

      f32x4 r0[8];
      LOAD8(r0, hbase(h0ring + ((u - 1) & 7) * BH));
      WAIT8(r0);
      stage_write(r0);
      __syncthreads();

      float acc[4][4] = {{0.f}};
#pragma unroll 4
      for (int i = 0; i < 32; ++i) {
        int k = ks + 32 * i;
        float4 hv = *(const float4*)&hT[k * 16 + 4 * bq];
        float4 wv = *(const float4*)&wT[k * 16 + 4 * rq];
        float hb[4] = {hv.x, hv.y, hv.z, hv.w};
        float wr[4] = {wv.x, wv.y, wv.z, wv.w};
#pragma unroll
        for (int b_ = 0; b_ < 4; ++b_)
#pragma unroll
          for (int rj = 0; rj < 4; ++rj)
            acc[b_][rj] = fmaf(hb[b_], wr[rj], acc[b_][rj]);
      }
#pragma unroll
      for (int b_ = 0; b_ < 4; ++b_)
#pragma unroll
        for (int rj = 0; rj < 4; ++rj) {
          float v = acc[b_][rj];
          v += __shfl_xor(v, 16); v += __shfl_xor(v, 32);
          acc[b_][rj] = v;
        }
      const int w = tid >> 6;
      if ((tid & 63) < 16) {
#pragma unroll
        for (int b_ = 0; b_ < 4; ++b_)
#pragma unroll
          for (int rj = 0; rj < 4; ++rj)
            part[w * 256 + (4*bq + b_) * 16 + 4*rq + rj] = acc[b_][rj];
      }
      __syncthreads();
      if (tid < 256) {
        int b = tid >> 4, r = tid & 15;
        float s = myPre;
#pragma unroll
        for (int w2 = 0; w2 < 8; ++w2) s += part[w2 * 256 + b * 16 + r];
        st_coherent(h0ring + (u & 7) * BH + (size_t)b * HID + 16 * blk + r, tanhf(s));
      }
      asm volatile("s_waitcnt vmcnt(0)" ::: "memory");
      __syncthreads();
      if (tid == 0) {
        __hip_atomic_fetch_add(bar + (blk & 3) * 32, 1,
                               __ATOMIC_RELAXED, __HIP_MEMORY_SCOPE_AGENT);
        if (blk == 0) {                       // L0 master publishes go0
          const int target = NL0 * (u + 1);
          for (;;) {
            int s = 0;
#pragma unroll
            for (int i = 0; i < 4; ++i) s += ld_rlx(bar + i * 32);
            if (s >= target) break;
          }
          st_rlx(go0, u + 1);
        }
      }
    }
  } else {
    // =============================== L1 ===================================
    const int bq = tid & 3, rq = (tid >> 2) & 1, ks = tid >> 3;  // ks 0..63
    for (int t = 0; t < SEQ; ++t) {
      if (tid == 0) {
        while (ld_rlx(go0) < t + 1) __builtin_amdgcn_s_sleep(1);
        if (t)
          while (ld_rlx(go1) < t) __builtin_amdgcn_s_sleep(1);
      }
      __syncthreads();

      f32x4 r0[8], r1[8];
      LOAD8(r0, hbase(h0ring + (t & 7) * BH));
      LOAD8(r1, hbase(h1g + ((t - 1) & 1) * BH));
      WAIT16(r0, r1);
      stage_write(r0);
      __syncthreads();

      float acc[4][4] = {{0.f}};
      // phase A: Wi1 . h0[t]
#pragma unroll 4
      for (int i = 0; i < 16; ++i) {
        int k = ks + 64 * i;
        float4 hv = *(const float4*)&hT[k * 16 + 4 * bq];
        float4 wv = *(const float4*)&wT[k * 8 + 4 * rq];
        float hb[4] = {hv.x, hv.y, hv.z, hv.w};
        float wr[4] = {wv.x, wv.y, wv.z, wv.w};
#pragma unroll
        for (int b_ = 0; b_ < 4; ++b_)
#pragma unroll
          for (int rj = 0; rj < 4; ++rj)
            acc[b_][rj] = fmaf(hb[b_], wr[rj], acc[b_][rj]);
      }
      __syncthreads();   // done reading hT
      stage_write(r1);
      __syncthreads();
      // phase B: Wh1 . h1[t-1]
#pragma unroll 4
      for (int i = 0; i < 16; ++i) {
        int k = ks + 64 * i;
        float4 hv = *(const float4*)&hT[k * 16 + 4 * bq];
        float4 wv = *(const float4*)&wT[(1024 + k) * 8 + 4 * rq];
        float hb[4] = {hv.x, hv.y, hv.z, hv.w};
        float wr[4] = {wv.x, wv.y, wv.z, wv.w};
#pragma unroll
        for (int b_ = 0; b_ < 4; ++b_)
#pragma unroll
          for (int rj = 0; rj < 4; ++rj)
            acc[b_][rj] = fmaf(hb[b_], wr[rj], acc[b_][rj]);
      }
#pragma unroll
      for (int b_ = 0; b_ < 4; ++b_)
#pragma unroll
        for (int rj = 0; rj < 4; ++rj) {
          float v = acc[b_][rj];
          v += __shfl_xor(v, 8); v += __shfl_xor(v, 16); v += __shfl_xor(v, 32);
          acc[b_][rj] = v;
        }
      const int w = tid >> 6;
      if ((tid & 63) < 8) {
#pragma unroll
        for (int b_ = 0; b_ < 4; ++b_)
#pragma unroll
          for (int rj = 0; rj < 4; ++rj)
            part[w * 128 + (4*bq + b_) * 8 + 4*rq + rj] = acc[b_][rj];
      }
      __syncthreads();
      if (tid < 128) {
        int b = tid >> 3, r = tid & 7;
        float s = bias[r];
#pragma unroll
        for (int w2 = 0; w2 < 8; ++w2) s += part[w2 * 128 + b * 8 + r];
        int R = 8 * (blk - NL0) + r;
        float v = tanhf(s);
        tops[((size_t)t * BATCH + b) * HID + R] = v;   // read after kernel end
        st_coherent(h1g + (t & 1) * BH + (size_t)b * HID + R, v);
      }
      asm volatile("s_waitcnt vmcnt(0)" ::: "memory");
      __syncthreads();
      if (tid == 0) {
        __hip_atomic_fetch_add(bar + (4 + (blk & 3)) * 32, 1,
                               __ATOMIC_RELAXED, __HIP_MEMORY_SCOPE_AGENT);
        if (blk == NL0) {                     // L1 master publishes go1
          const int target = NL1 * (t + 1);
          for (;;) {
            int s = 0;
#pragma unroll
            for (int i = 0; i < 4; ++i) s += ld_rlx(bar + (4 + i) * 32);
            if (s >= target) break;
          }
          st_rlx(go1, t + 1);
        }
      }
    }
  }
}

// ---------------------------------------------------------------------------
// logits = tops . Wo^T + bo via split-bf16 MFMA (unchanged, passed r3-r8).
// ---------------------------------------------------------------------------
__global__ __launch_bounds__(512, 1) void proj_mfma(
    const float* __restrict__ tops, const float* __restrict__ Wo,
    const float* __restrict__ bo, float* __restrict__ out)
{
  __shared__ ushort Ahi[256 * 64];
  __shared__ ushort Alo[256 * 64];
  __shared__ ushort Bs [256 * 64];
  const int tid  = threadIdx.x;
  const int m0   = blockIdx.x * 256;
  const int n0   = blockIdx.y * 256;
  const int lane = tid & 63, wv = tid >> 6;
  const int wm   = wv & 3, wn = wv >> 2;
  const int bconst = blockIdx.x;

  f32x4 acc[4][8];
#pragma unroll
  for (int i = 0; i < 4; ++i)
#pragma unroll
    for (int j = 0; j < 8; ++j) acc[i][j] = (f32x4)0.f;

  const int sr = tid >> 4;
  const int sk = (tid & 15) * 4;

  for (int kt = 0; kt < HID; kt += 64) {
    __syncthreads();
#pragma unroll
    for (int p = 0; p < 8; ++p) {
      int r = sr + 32 * p;
      float4 v = *(const float4*)(tops + ((size_t)r * BATCH + bconst) * HID + kt + sk);
      float f[4] = {v.x, v.y, v.z, v.w};
      ushort hi[4], lo[4];
#pragma unroll
      for (int c = 0; c < 4; ++c) {
        hi[c] = f2bf(f[c]);
        lo[c] = f2bf(f[c] - bf2f(hi[c]));
      }
      uint off = (uint)(r * 128 + sk * 2) ^ (uint)((r & 7) << 4);
      *(ushort4*)((char*)Ahi + off) = make_ushort4(hi[0], hi[1], hi[2], hi[3]);
      *(ushort4*)((char*)Alo + off) = make_ushort4(lo[0], lo[1], lo[2], lo[3]);
    }
#pragma unroll
    for (int p = 0; p < 8; ++p) {
      int r = sr + 32 * p;
      float4 v = *(const float4*)(Wo + (size_t)(n0 + r) * HID + kt + sk);
      uint off = (uint)(r * 128 + sk * 2) ^ (uint)((r & 7) << 4);
      *(ushort4*)((char*)Bs + off) =
          make_ushort4(f2bf(v.x), f2bf(v.y), f2bf(v.z), f2bf(v.w));
    }
    __syncthreads();

    const int fr = lane & 15, kg = lane >> 4;
#pragma unroll
    for (int kk = 0; kk < 2; ++kk) {
      short8 bf[8], ah[4], al[4];
#pragma unroll
      for (int nf = 0; nf < 8; ++nf) {
        int row = wn * 128 + nf * 16 + fr;
        uint off = (uint)(row * 128 + kk * 64 + kg * 16) ^ (uint)((row & 7) << 4);
        bf[nf] = *(const short8*)((const char*)Bs + off);
      }
#pragma unroll
      for (int mf = 0; mf < 4; ++mf) {
        int row = wm * 64 + mf * 16 + fr;
        uint off = (uint)(row * 128 + kk * 64 + kg * 16) ^ (uint)((row & 7) << 4);
        ah[mf] = *(const short8*)((const char*)Ahi + off);
        al[mf] = *(const short8*)((const char*)Alo + off);
      }
#pragma unroll
      for (int mf = 0; mf < 4; ++mf)
#pragma unroll
        for (int nf = 0; nf < 8; ++nf) {
          acc[mf][nf] = __builtin_amdgcn_mfma_f32_16x16x32_bf16(
              ah[mf], bf[nf], acc[mf][nf], 0, 0, 0);
          acc[mf][nf] = __builtin_amdgcn_mfma_f32_16x16x32_bf16(
              al[mf], bf[nf], acc[mf][nf], 0, 0, 0);
        }
    }
  }

  const int fr = lane & 15, rg = lane >> 4;
#pragma unroll
  for (int mf = 0; mf < 4; ++mf)
#pragma unroll
    for (int nf = 0; nf < 8; ++nf) {
      int n = n0 + wn * 128 + nf * 16 + fr;
      float bb = bo[n];
#pragma unroll
      for (int j = 0; j < 4; ++j) {
        int m = m0 + wm * 64 + mf * 16 + rg * 4 + j;
        out[(size_t)m * VOCAB + n] = acc[mf][nf][j] + bb;
      }
    }
}

// hidden[0][b][n] = h0 step 255 (ring slot 255&7 = 7); hidden[1] = tops[255]
__global__ void copy_hidden(const float* __restrict__ h0ring,
                            const float* __restrict__ tops,
                            float* __restrict__ outh)
{
  int i = blockIdx.x * 256 + threadIdx.x;   // 0..32767
  int l = i >> 14, rem = i & 16383;
  outh[i] = (l == 0) ? h0ring[7 * BH + rem]
                     : tops[(size_t)(SEQ - 1) * BH + rem];
}

extern "C" void kernel_launch(void* const* d_in, const int* in_sizes, int n_in,
                              void* d_out, int out_size, void* d_ws, size_t ws_size,
                              hipStream_t stream)
{
  const int*   x     = (const int*)d_in[0];
  const float* embed = (const float*)d_in[1];
  const float* Wi    = (const float*)d_in[2];
  const float* bi    = (const float*)d_in[3];
  const float* Wh    = (const float*)d_in[4];
  const float* bh    = (const float*)d_in[5];
  const float* Wo    = (const float*)d_in[6];
  const float* bo    = (const float*)d_in[7];
  float* out = (float*)d_out;

  char* ws = (char*)d_ws;
  float* pre0   = (float*)(ws);                           // 16 MiB [t][b][n]
  float* tops   = (float*)(ws + (16u << 20));             // 16 MiB [t][b][n]
  float* h0ring = (float*)(ws + (32u << 20));             // 8 x 64 KiB ring
  float* h1g    = (float*)(ws + (32u << 20) + 524288);    // 2 x 64 KiB
  int*   bar    = (int*)  (ws + (32u << 20) + 655360);    // arrivals + go flags

  // zero ring + h1 parities + counters (deterministic across replays)
  hipMemsetAsync(h0ring, 0, 655360 + 4096, stream);

  pre0_gemm<<<dim3(8, 32), dim3(256), 0, stream>>>(x, embed, Wi, bi, bh, pre0);

  void* args[] = { (void*)&Wi, (void*)&Wh, (void*)&bi, (void*)&bh,
                   (void*)&pre0, (void*)&h0ring, (void*)&h1g, (void*)&tops,
                   (void*)&bar };
  hipLaunchCooperativeKernel((void*)rnn_scan, dim3(NBLK), dim3(512), args, 0, stream);

  proj_mfma<<<dim3(16, 125), dim3(512), 0, stream>>>(tops, Wo, bo, out);

  copy_hidden<<<dim3(128), dim3(256), 0, stream>>>(
      h0ring, tops, out + (size_t)BATCH * SEQ * VOCAB);
}

// Round 10
// 2894.555 us; speedup vs baseline: 2.2650x; 1.0980x over previous
//
#include <hip/hip_runtime.h>
#include <cmath>
#include <cstdint>

#define VOCAB 32000
#define HID   1024
#define BATCH 16
#define SEQ   256
#define NL0   64
#define NL1   128
#define MASTER (NL0 + NL1)        // block 192: dedicated sync master
#define NBLK  (NL0 + NL1 + 1)
#define BH    (BATCH * HID)

typedef __attribute__((ext_vector_type(8))) short short8;
typedef __attribute__((ext_vector_type(4))) float f32x4;

__device__ __forceinline__ ushort f2bf(float f) {  // RNE fp32 -> bf16 bits
  uint u = __builtin_bit_cast(uint, f);
  return (ushort)((u + 0x7FFFu + ((u >> 16) & 1u)) >> 16);
}
__device__ __forceinline__ float bf2f(ushort h) {
  return __builtin_bit_cast(float, (uint)h << 16);
}

// ---- MALL-coherent vector load/store (sc0 sc1), early-clobber outputs ----
#define LOAD8(d, base)                                                        \
  asm volatile(                                                               \
    "global_load_dwordx4 %0, %8, off sc0 sc1\n\t"                             \
    "global_load_dwordx4 %1, %8, off offset:512 sc0 sc1\n\t"                  \
    "global_load_dwordx4 %2, %8, off offset:1024 sc0 sc1\n\t"                 \
    "global_load_dwordx4 %3, %8, off offset:1536 sc0 sc1\n\t"                 \
    "global_load_dwordx4 %4, %8, off offset:2048 sc0 sc1\n\t"                 \
    "global_load_dwordx4 %5, %8, off offset:2560 sc0 sc1\n\t"                 \
    "global_load_dwordx4 %6, %8, off offset:3072 sc0 sc1\n\t"                 \
    "global_load_dwordx4 %7, %8, off offset:3584 sc0 sc1"                     \
    : "=&v"(d[0]), "=&v"(d[1]), "=&v"(d[2]), "=&v"(d[3]),                     \
      "=&v"(d[4]), "=&v"(d[5]), "=&v"(d[6]), "=&v"(d[7])                      \
    : "v"(base) : "memory")

#define WAIT8(d)                                                              \
  asm volatile("s_waitcnt vmcnt(0)"                                           \
    : "+v"(d[0]), "+v"(d[1]), "+v"(d[2]), "+v"(d[3]),                         \
      "+v"(d[4]), "+v"(d[5]), "+v"(d[6]), "+v"(d[7]) :: "memory")

__device__ __forceinline__ void st_coherent(float* p, float v) {
  asm volatile("global_store_dword %0, %1, off sc0 sc1" :: "v"(p), "v"(v) : "memory");
}
__device__ __forceinline__ int ld_rlx(const int* p) {
  return __hip_atomic_load(p, __ATOMIC_RELAXED, __HIP_MEMORY_SCOPE_AGENT);
}
__device__ __forceinline__ void st_rlx(int* p, int v) {
  __hip_atomic_store(p, v, __ATOMIC_RELAXED, __HIP_MEMORY_SCOPE_AGENT);
}

// ---------------------------------------------------------------------------
// pre0[t][b][n] = embed[x[b][t]] . Wi0[n] + bi0[n] + bh0[n]   (unchanged)
// ---------------------------------------------------------------------------
__global__ __launch_bounds__(256) void pre0_gemm(
    const int* __restrict__ x, const float* __restrict__ embed,
    const float* __restrict__ Wi0, const float* __restrict__ bi0,
    const float* __restrict__ bh0, float* __restrict__ pre)
{
  __shared__ float As[32][132];
  __shared__ float Bs[32][132];
  const int tid  = threadIdx.x;
  const int n0   = blockIdx.x * 128;
  const int m0   = blockIdx.y * 128;
  const int lrow = tid >> 3, lkq = tid & 7;
  const int ty   = tid >> 4, tx  = tid & 15;

  const float* arow[4];
#pragma unroll
  for (int q = 0; q < 4; ++q) {
    int m = m0 + lrow + 32 * q;
    int t = m >> 4, b = m & 15;
    arow[q] = embed + (size_t)x[b * SEQ + t] * HID;
  }
  const float* brow = Wi0 + (size_t)(n0 + lrow) * HID;

  float acc[8][8];
#pragma unroll
  for (int i = 0; i < 8; ++i)
#pragma unroll
    for (int j = 0; j < 8; ++j) acc[i][j] = 0.f;

  for (int kt = 0; kt < HID; kt += 32) {
    float4 av[4], bv[4];
#pragma unroll
    for (int q = 0; q < 4; ++q) {
      av[q] = *(const float4*)(arow[q] + kt + lkq * 4);
      bv[q] = *(const float4*)(brow + (size_t)(32 * q) * HID + kt + lkq * 4);
    }
    __syncthreads();
#pragma unroll
    for (int q = 0; q < 4; ++q) {
      int r = lrow + 32 * q;
      As[lkq*4+0][r] = av[q].x; As[lkq*4+1][r] = av[q].y;
      As[lkq*4+2][r] = av[q].z; As[lkq*4+3][r] = av[q].w;
      Bs[lkq*4+0][r] = bv[q].x; Bs[lkq*4+1][r] = bv[q].y;
      Bs[lkq*4+2][r] = bv[q].z; Bs[lkq*4+3][r] = bv[q].w;
    }
    __syncthreads();
#pragma unroll
    for (int kk = 0; kk < 32; ++kk) {
      float4 a0 = *(const float4*)&As[kk][ty * 8];
      float4 a1 = *(const float4*)&As[kk][ty * 8 + 4];
      float4 b0 = *(const float4*)&Bs[kk][tx * 8];
      float4 b1 = *(const float4*)&Bs[kk][tx * 8 + 4];
      float a[8] = {a0.x,a0.y,a0.z,a0.w,a1.x,a1.y,a1.z,a1.w};
      float b[8] = {b0.x,b0.y,b0.z,b0.w,b1.x,b1.y,b1.z,b1.w};
#pragma unroll
      for (int i = 0; i < 8; ++i)
#pragma unroll
        for (int j = 0; j < 8; ++j) acc[i][j] = fmaf(a[i], b[j], acc[i][j]);
    }
  }

#pragma unroll
  for (int i = 0; i < 8; ++i) {
    int m = m0 + ty * 8 + i;
    float* o = pre + (size_t)m * HID + n0 + tx * 8;
#pragma unroll
    for (int j = 0; j < 8; ++j) {
      int n = n0 + tx * 8 + j;
      o[j] = acc[i][j] + bi0[n] + bh0[n];
    }
  }
}

// ---------------------------------------------------------------------------
// Decoupled 2-cohort scan + DEDICATED sync-master block.
//  bar lines (128B apart): 0..3 L0 arrivals (blk&3), 4..11 L1 arrivals
//  (blk&7), 12 = go0 epoch, 13 = go1 epoch.
//  L0 (blocks 0..63, 16 rows Wh0): tick u writes h0ring slot u&7.
//     gates: go0 >= u ; go1 >= u-7 (ring safety).
//  L1 (blocks 64..191, 8 rows [Wi1|Wh1]): step t writes h1[t&1], tops[t].
//     PHASE-A HOIST: load/stage/compute Wi1.h0[t] (gate go0 >= t+1, L0 runs
//     ahead so this rarely blocks) BEFORE the serial gate go1 >= t; only the
//     h1-dependent phase-B sits on the critical chain.
//  Master (block 192, tid 0): continuously polls arrivals, publishes epochs.
// Ordering: h stores sc0sc1 + vmcnt(0) + barrier BEFORE arrival RMW;
// consumers load h sc0sc1 only after observing the go epoch.
// ---------------------------------------------------------------------------
__global__ __launch_bounds__(512) void rnn_scan(
    const float* __restrict__ Wi, const float* __restrict__ Wh,
    const float* __restrict__ bi, const float* __restrict__ bh,
    const float* __restrict__ pre0, float* __restrict__ h0ring,
    float* __restrict__ h1g, float* __restrict__ tops,
    int* __restrict__ bar)
{
  const int tid = threadIdx.x;
  const int blk = blockIdx.x;
  int* go0 = bar + 12 * 32;
  int* go1 = bar + 13 * 32;

  if (blk == MASTER) {                 // ---- dedicated sync master ----
    if (tid == 0) {
      int e0 = 0, e1 = 0;
      while (e0 < SEQ || e1 < SEQ) {
        int s0 = 0, s1 = 0;
#pragma unroll
        for (int i = 0; i < 4; ++i) s0 += ld_rlx(bar + i * 32);
#pragma unroll
        for (int i = 0; i < 8; ++i) s1 += ld_rlx(bar + (4 + i) * 32);
        int n0 = s0 >> 6;              // /64  completed L0 epochs
        int n1 = s1 >> 7;              // /128 completed L1 epochs
        if (n0 > e0) { e0 = n0; st_rlx(go0, e0); }
        if (n1 > e1) { e1 = n1; st_rlx(go1, e1); }
      }
    }
    return;
  }

  __shared__ float wT[16 * 1024];   // L0: [k][16]; L1: [k2][8], k2<2048
  __shared__ float hT[1024 * 16];   // [k][16] staged h
  __shared__ float part[2048];
  __shared__ float bias[8];

  const bool isL0 = (blk < NL0);

  if (isL0) {
    const int j = blk;
#pragma unroll
    for (int p = 0; p < 8; ++p) {
      int idx = tid + 512 * p;
      int r = idx >> 8, kq = idx & 255;
      float4 v = *(const float4*)(Wh + ((size_t)(16 * j + r)) * HID + 4 * kq);
      wT[(4*kq+0)*16 + r] = v.x; wT[(4*kq+1)*16 + r] = v.y;
      wT[(4*kq+2)*16 + r] = v.z; wT[(4*kq+3)*16 + r] = v.w;
    }
  } else {
    const int j = blk - NL0;
#pragma unroll
    for (int p = 0; p < 8; ++p) {
      int idx = tid + 512 * p;
      int half = idx >> 11;
      int id2 = idx & 2047;
      int r = id2 >> 8, kq = id2 & 255;
      const float* W = (half ? Wh : Wi) + (size_t)HID * HID;
      float4 v = *(const float4*)(W + ((size_t)(8 * j + r)) * HID + 4 * kq);
      int kb = half * 1024 + 4 * kq;
      wT[(kb+0)*8 + r] = v.x; wT[(kb+1)*8 + r] = v.y;
      wT[(kb+2)*8 + r] = v.z; wT[(kb+3)*8 + r] = v.w;
    }
    if (tid < 8) bias[tid] = bi[HID + 8 * j + tid] + bh[HID + 8 * j + tid];
  }
  __syncthreads();

  const int sb  = tid & 15;
  const int skq = tid >> 4;
  auto hbase = [&](const float* src) {
    return (const float*)((const char*)src + sb * 4096 + skq * 16);
  };
  auto stage_write = [&](const f32x4* d) {
#pragma unroll
    for (int p = 0; p < 8; ++p) {
      int kq = skq + 32 * p;
#pragma unroll
      for (int c = 0; c < 4; ++c) hT[(4*kq+c)*16 + sb] = d[p][c];
    }
  };

  if (isL0) {
    // =============================== L0 ===================================
    const int bq = tid & 3, rq = (tid >> 2) & 3, ks = tid >> 4;  // ks 0..31
    for (int u = 0; u < SEQ; ++u) {
      float myPre = 0.f;               // gate-independent prefetch
      if (tid < 256)
        myPre = pre0[((size_t)u * BATCH + (tid >> 4)) * HID + 16 * blk + (tid & 15)];

      if (tid == 0) {
        while (ld_rlx(go0) < u) __builtin_amdgcn_s_sleep(1);
        const int need = u - 7;
        if (need > 0)
          while (ld_rlx(go1) < need) __builtin_amdgcn_s_sleep(1);
      }
      __syncthreads();

      f32x4 r0[8];
      LOAD8(r0, hbase(h0ring + ((u - 1) & 7) * BH));
      WAIT8(r0);
      stage_write(r0);
      __syncthreads();

      float acc[4][4] = {{0.f}};
#pragma unroll 4
      for (int i = 0; i < 32; ++i) {
        int k = ks + 32 * i;
        float4 hv = *(const float4*)&hT[k * 16 + 4 * bq];
        float4 wv = *(const float4*)&wT[k * 16 + 4 * rq];
        float hb[4] = {hv.x, hv.y, hv.z, hv.w};
        float wr[4] = {wv.x, wv.y, wv.z, wv.w};
#pragma unroll
        for (int b_ = 0; b_ < 4; ++b_)
#pragma unroll
          for (int rj = 0; rj < 4; ++rj)
            acc[b_][rj] = fmaf(hb[b_], wr[rj], acc[b_][rj]);
      }
#pragma unroll
      for (int b_ = 0; b_ < 4; ++b_)
#pragma unroll
        for (int rj = 0; rj < 4; ++rj) {
          float v = acc[b_][rj];
          v += __shfl_xor(v, 16); v += __shfl_xor(v, 32);
          acc[b_][rj] = v;
        }
      const int w = tid >> 6;
      if ((tid & 63) < 16) {
#pragma unroll
        for (int b_ = 0; b_ < 4; ++b_)
#pragma unroll
          for (int rj = 0; rj < 4; ++rj)
            part[w * 256 + (4*bq + b_) * 16 + 4*rq + rj] = acc[b_][rj];
      }
      __syncthreads();
      if (tid < 256) {
        int b = tid >> 4, r = tid & 15;
        float s = myPre;
#pragma unroll
        for (int w2 = 0; w2 < 8; ++w2) s += part[w2 * 256 + b * 16 + r];
        st_coherent(h0ring + (u & 7) * BH + (size_t)b * HID + 16 * blk + r, tanhf(s));
      }
      asm volatile("s_waitcnt vmcnt(0)" ::: "memory");
      __syncthreads();
      if (tid == 0)
        __hip_atomic_fetch_add(bar + (blk & 3) * 32, 1,
                               __ATOMIC_RELAXED, __HIP_MEMORY_SCOPE_AGENT);
    }
  } else {
    // =============================== L1 ===================================
    const int bq = tid & 3, rq = (tid >> 2) & 1, ks = tid >> 3;  // ks 0..63
    for (int t = 0; t < SEQ; ++t) {
      // ---- phase A (off critical chain): Wi1 . h0[t] ----
      if (tid == 0)
        while (ld_rlx(go0) < t + 1) __builtin_amdgcn_s_sleep(1);
      __syncthreads();

      f32x4 r0[8];
      LOAD8(r0, hbase(h0ring + (t & 7) * BH));
      WAIT8(r0);
      stage_write(r0);
      __syncthreads();

      float acc[4][4] = {{0.f}};
#pragma unroll 4
      for (int i = 0; i < 16; ++i) {
        int k = ks + 64 * i;
        float4 hv = *(const float4*)&hT[k * 16 + 4 * bq];
        float4 wv = *(const float4*)&wT[k * 8 + 4 * rq];
        float hb[4] = {hv.x, hv.y, hv.z, hv.w};
        float wr[4] = {wv.x, wv.y, wv.z, wv.w};
#pragma unroll
        for (int b_ = 0; b_ < 4; ++b_)
#pragma unroll
          for (int rj = 0; rj < 4; ++rj)
            acc[b_][rj] = fmaf(hb[b_], wr[rj], acc[b_][rj]);
      }

      // ---- serial gate: h1[t-1] ready ----
      if (tid == 0 && t)
        while (ld_rlx(go1) < t) __builtin_amdgcn_s_sleep(1);
      __syncthreads();                 // gate passed AND all done reading hT

      f32x4 r1[8];
      LOAD8(r1, hbase(h1g + ((t - 1) & 1) * BH));
      WAIT8(r1);
      stage_write(r1);
      __syncthreads();

      // ---- phase B: Wh1 . h1[t-1] ----
#pragma unroll 4
      for (int i = 0; i < 16; ++i) {
        int k = ks + 64 * i;
        float4 hv = *(const float4*)&hT[k * 16 + 4 * bq];
        float4 wv = *(const float4*)&wT[(1024 + k) * 8 + 4 * rq];
        float hb[4] = {hv.x, hv.y, hv.z, hv.w};
        float wr[4] = {wv.x, wv.y, wv.z, wv.w};
#pragma unroll
        for (int b_ = 0; b_ < 4; ++b_)
#pragma unroll
          for (int rj = 0; rj < 4; ++rj)
            acc[b_][rj] = fmaf(hb[b_], wr[rj], acc[b_][rj]);
      }
#pragma unroll
      for (int b_ = 0; b_ < 4; ++b_)
#pragma unroll
        for (int rj = 0; rj < 4; ++rj) {
          float v = acc[b_][rj];
          v += __shfl_xor(v, 8); v += __shfl_xor(v, 16); v += __shfl_xor(v, 32);
          acc[b_][rj] = v;
        }
      const int w = tid >> 6;
      if ((tid & 63) < 8) {
#pragma unroll
        for (int b_ = 0; b_ < 4; ++b_)
#pragma unroll
          for (int rj = 0; rj < 4; ++rj)
            part[w * 128 + (4*bq + b_) * 8 + 4*rq + rj] = acc[b_][rj];
      }
      __syncthreads();
      if (tid < 128) {
        int b = tid >> 3, r = tid & 7;
        float s = bias[r];
#pragma unroll
        for (int w2 = 0; w2 < 8; ++w2) s += part[w2 * 128 + b * 8 + r];
        int R = 8 * (blk - NL0) + r;
        float v = tanhf(s);
        tops[((size_t)t * BATCH + b) * HID + R] = v;   // read after kernel end
        st_coherent(h1g + (t & 1) * BH + (size_t)b * HID + R, v);
      }
      asm volatile("s_waitcnt vmcnt(0)" ::: "memory");
      __syncthreads();
      if (tid == 0)
        __hip_atomic_fetch_add(bar + (4 + (blk & 7)) * 32, 1,
                               __ATOMIC_RELAXED, __HIP_MEMORY_SCOPE_AGENT);
    }
  }
}

// ---------------------------------------------------------------------------
// logits = tops . Wo^T + bo via split-bf16 MFMA (unchanged, passed r3-r9).
// ---------------------------------------------------------------------------
__global__ __launch_bounds__(512, 1) void proj_mfma(
    const float* __restrict__ tops, const float* __restrict__ Wo,
    const float* __restrict__ bo, float* __restrict__ out)
{
  __shared__ ushort Ahi[256 * 64];
  __shared__ ushort Alo[256 * 64];
  __shared__ ushort Bs [256 * 64];
  const int tid  = threadIdx.x;
  const int m0   = blockIdx.x * 256;
  const int n0   = blockIdx.y * 256;
  const int lane = tid & 63, wv = tid >> 6;
  const int wm   = wv & 3, wn = wv >> 2;
  const int bconst = blockIdx.x;

  f32x4 acc[4][8];
#pragma unroll
  for (int i = 0; i < 4; ++i)
#pragma unroll
    for (int j = 0; j < 8; ++j) acc[i][j] = (f32x4)0.f;

  const int sr = tid >> 4;
  const int sk = (tid & 15) * 4;

  for (int kt = 0; kt < HID; kt += 64) {
    __syncthreads();
#pragma unroll
    for (int p = 0; p < 8; ++p) {
      int r = sr + 32 * p;
      float4 v = *(const float4*)(tops + ((size_t)r * BATCH + bconst) * HID + kt + sk);
      float f[4] = {v.x, v.y, v.z, v.w};
      ushort hi[4], lo[4];
#pragma unroll
      for (int c = 0; c < 4; ++c) {
        hi[c] = f2bf(f[c]);
        lo[c] = f2bf(f[c] - bf2f(hi[c]));
      }
      uint off = (uint)(r * 128 + sk * 2) ^ (uint)((r & 7) << 4);
      *(ushort4*)((char*)Ahi + off) = make_ushort4(hi[0], hi[1], hi[2], hi[3]);
      *(ushort4*)((char*)Alo + off) = make_ushort4(lo[0], lo[1], lo[2], lo[3]);
    }
#pragma unroll
    for (int p = 0; p < 8; ++p) {
      int r = sr + 32 * p;
      float4 v = *(const float4*)(Wo + (size_t)(n0 + r) * HID + kt + sk);
      uint off = (uint)(r * 128 + sk * 2) ^ (uint)((r & 7) << 4);
      *(ushort4*)((char*)Bs + off) =
          make_ushort4(f2bf(v.x), f2bf(v.y), f2bf(v.z), f2bf(v.w));
    }
    __syncthreads();

    const int fr = lane & 15, kg = lane >> 4;
#pragma unroll
    for (int kk = 0; kk < 2; ++kk) {
      short8 bf[8], ah[4], al[4];
#pragma unroll
      for (int nf = 0; nf < 8; ++nf) {
        int row = wn * 128 + nf * 16 + fr;
        uint off = (uint)(row * 128 + kk * 64 + kg * 16) ^ (uint)((row & 7) << 4);
        bf[nf] = *(const short8*)((const char*)Bs + off);
      }
#pragma unroll
      for (int mf = 0; mf < 4; ++mf) {
        int row = wm * 64 + mf * 16 + fr;
        uint off = (uint)(row * 128 + kk * 64 + kg * 16) ^ (uint)((row & 7) << 4);
        ah[mf] = *(const short8*)((const char*)Ahi + off);
        al[mf] = *(const short8*)((const char*)Alo + off);
      }
#pragma unroll
      for (int mf = 0; mf < 4; ++mf)
#pragma unroll
        for (int nf = 0; nf < 8; ++nf) {
          acc[mf][nf] = __builtin_amdgcn_mfma_f32_16x16x32_bf16(
              ah[mf], bf[nf], acc[mf][nf], 0, 0, 0);
          acc[mf][nf] = __builtin_amdgcn_mfma_f32_16x16x32_bf16(
              al[mf], bf[nf], acc[mf][nf], 0, 0, 0);
        }
    }
  }

  const int fr = lane & 15, rg = lane >> 4;
#pragma unroll
  for (int mf = 0; mf < 4; ++mf)
#pragma unroll
    for (int nf = 0; nf < 8; ++nf) {
      int n = n0 + wn * 128 + nf * 16 + fr;
      float bb = bo[n];
#pragma unroll
      for (int j = 0; j < 4; ++j) {
        int m = m0 + wm * 64 + mf * 16 + rg * 4 + j;
        out[(size_t)m * VOCAB + n] = acc[mf][nf][j] + bb;
      }
    }
}

// hidden[0][b][n] = h0 step 255 (ring slot 7); hidden[1] = tops[255]
__global__ void copy_hidden(const float* __restrict__ h0ring,
                            const float* __restrict__ tops,
                            float* __restrict__ outh)
{
  int i = blockIdx.x * 256 + threadIdx.x;   // 0..32767
  int l = i >> 14, rem = i & 16383;
  outh[i] = (l == 0) ? h0ring[7 * BH + rem]
                     : tops[(size_t)(SEQ - 1) * BH + rem];
}

extern "C" void kernel_launch(void* const* d_in, const int* in_sizes, int n_in,
                              void* d_out, int out_size, void* d_ws, size_t ws_size,
                              hipStream_t stream)
{
  const int*   x     = (const int*)d_in[0];
  const float* embed = (const float*)d_in[1];
  const float* Wi    = (const float*)d_in[2];
  const float* bi    = (const float*)d_in[3];
  const float* Wh    = (const float*)d_in[4];
  const float* bh    = (const float*)d_in[5];
  const float* Wo    = (const float*)d_in[6];
  const float* bo    = (const float*)d_in[7];
  float* out = (float*)d_out;

  char* ws = (char*)d_ws;
  float* pre0   = (float*)(ws);                           // 16 MiB [t][b][n]
  float* tops   = (float*)(ws + (16u << 20));             // 16 MiB [t][b][n]
  float* h0ring = (float*)(ws + (32u << 20));             // 8 x 64 KiB ring
  float* h1g    = (float*)(ws + (32u << 20) + 524288);    // 2 x 64 KiB
  int*   bar    = (int*)  (ws + (32u << 20) + 655360);    // arrivals + go flags

  // zero ring + h1 parities + counters (deterministic across replays)
  hipMemsetAsync(h0ring, 0, 655360 + 4096, stream);

  pre0_gemm<<<dim3(8, 32), dim3(256), 0, stream>>>(x, embed, Wi, bi, bh, pre0);

  void* args[] = { (void*)&Wi, (void*)&Wh, (void*)&bi, (void*)&bh,
                   (void*)&pre0, (void*)&h0ring, (void*)&h1g, (void*)&tops,
                   (void*)&bar };
  hipLaunchCooperativeKernel((void*)rnn_scan, dim3(NBLK), dim3(512), args, 0, stream);

  proj_mfma<<<dim3(16, 125), dim3(512), 0, stream>>>(tops, Wo, bo, out);

  copy_hidden<<<dim3(128), dim3(256), 0, stream>>>(
      h0ring, tops, out + (size_t)BATCH * SEQ * VOCAB);
}

// Round 11
// 2800.590 us; speedup vs baseline: 2.3410x; 1.0336x over previous
//
#include <hip/hip_runtime.h>
#include <cmath>
#include <cstdint>

#define VOCAB 32000
#define HID   1024
#define BATCH 16
#define SEQ   256
#define NL0   64
#define NL1   128
#define MASTER 192                 // block 192: sync master (then scavenges)
#define NBLK  256                  // 64 L0 + 128 L1 + 1 master + 63 helpers
#define BH    (BATCH * HID)
#define NTILE_M 16
#define NTILE_N 125
#define NTILES  (NTILE_M * NTILE_N)   // 2000 proj tiles (256x256)

typedef __attribute__((ext_vector_type(8))) short short8;
typedef __attribute__((ext_vector_type(4))) float f32x4;

__device__ __forceinline__ ushort f2bf(float f) {  // RNE fp32 -> bf16 bits
  uint u = __builtin_bit_cast(uint, f);
  return (ushort)((u + 0x7FFFu + ((u >> 16) & 1u)) >> 16);
}
__device__ __forceinline__ float bf2f(ushort h) {
  return __builtin_bit_cast(float, (uint)h << 16);
}

// ---- MALL-coherent vector load/store (sc0 sc1), early-clobber outputs ----
#define LOAD8(d, base)                                                        \
  asm volatile(                                                               \
    "global_load_dwordx4 %0, %8, off sc0 sc1\n\t"                             \
    "global_load_dwordx4 %1, %8, off offset:512 sc0 sc1\n\t"                  \
    "global_load_dwordx4 %2, %8, off offset:1024 sc0 sc1\n\t"                 \
    "global_load_dwordx4 %3, %8, off offset:1536 sc0 sc1\n\t"                 \
    "global_load_dwordx4 %4, %8, off offset:2048 sc0 sc1\n\t"                 \
    "global_load_dwordx4 %5, %8, off offset:2560 sc0 sc1\n\t"                 \
    "global_load_dwordx4 %6, %8, off offset:3072 sc0 sc1\n\t"                 \
    "global_load_dwordx4 %7, %8, off offset:3584 sc0 sc1"                     \
    : "=&v"(d[0]), "=&v"(d[1]), "=&v"(d[2]), "=&v"(d[3]),                     \
      "=&v"(d[4]), "=&v"(d[5]), "=&v"(d[6]), "=&v"(d[7])                      \
    : "v"(base) : "memory")

#define WAIT8(d)                                                              \
  asm volatile("s_waitcnt vmcnt(0)"                                           \
    : "+v"(d[0]), "+v"(d[1]), "+v"(d[2]), "+v"(d[3]),                         \
      "+v"(d[4]), "+v"(d[5]), "+v"(d[6]), "+v"(d[7]) :: "memory")

__device__ __forceinline__ void st_coherent(float* p, float v) {
  asm volatile("global_store_dword %0, %1, off sc0 sc1" :: "v"(p), "v"(v) : "memory");
}
__device__ __forceinline__ int ld_rlx(const int* p) {
  return __hip_atomic_load(p, __ATOMIC_RELAXED, __HIP_MEMORY_SCOPE_AGENT);
}
__device__ __forceinline__ void st_rlx(int* p, int v) {
  __hip_atomic_store(p, v, __ATOMIC_RELAXED, __HIP_MEMORY_SCOPE_AGENT);
}

// ---------------------------------------------------------------------------
// pre0[t][b][n] = embed[x[b][t]] . Wi0[n] + bi0[n] + bh0[n]   (unchanged)
// ---------------------------------------------------------------------------
__global__ __launch_bounds__(256) void pre0_gemm(
    const int* __restrict__ x, const float* __restrict__ embed,
    const float* __restrict__ Wi0, const float* __restrict__ bi0,
    const float* __restrict__ bh0, float* __restrict__ pre)
{
  __shared__ float As[32][132];
  __shared__ float Bs[32][132];
  const int tid  = threadIdx.x;
  const int n0   = blockIdx.x * 128;
  const int m0   = blockIdx.y * 128;
  const int lrow = tid >> 3, lkq = tid & 7;
  const int ty   = tid >> 4, tx  = tid & 15;

  const float* arow[4];
#pragma unroll
  for (int q = 0; q < 4; ++q) {
    int m = m0 + lrow + 32 * q;
    int t = m >> 4, b = m & 15;
    arow[q] = embed + (size_t)x[b * SEQ + t] * HID;
  }
  const float* brow = Wi0 + (size_t)(n0 + lrow) * HID;

  float acc[8][8];
#pragma unroll
  for (int i = 0; i < 8; ++i)
#pragma unroll
    for (int j = 0; j < 8; ++j) acc[i][j] = 0.f;

  for (int kt = 0; kt < HID; kt += 32) {
    float4 av[4], bv[4];
#pragma unroll
    for (int q = 0; q < 4; ++q) {
      av[q] = *(const float4*)(arow[q] + kt + lkq * 4);
      bv[q] = *(const float4*)(brow + (size_t)(32 * q) * HID + kt + lkq * 4);
    }
    __syncthreads();
#pragma unroll
    for (int q = 0; q < 4; ++q) {
      int r = lrow + 32 * q;
      As[lkq*4+0][r] = av[q].x; As[lkq*4+1][r] = av[q].y;
      As[lkq*4+2][r] = av[q].z; As[lkq*4+3][r] = av[q].w;
      Bs[lkq*4+0][r] = bv[q].x; Bs[lkq*4+1][r] = bv[q].y;
      Bs[lkq*4+2][r] = bv[q].z; Bs[lkq*4+3][r] = bv[q].w;
    }
    __syncthreads();
#pragma unroll
    for (int kk = 0; kk < 32; ++kk) {
      float4 a0 = *(const float4*)&As[kk][ty * 8];
      float4 a1 = *(const float4*)&As[kk][ty * 8 + 4];
      float4 b0 = *(const float4*)&Bs[kk][tx * 8];
      float4 b1 = *(const float4*)&Bs[kk][tx * 8 + 4];
      float a[8] = {a0.x,a0.y,a0.z,a0.w,a1.x,a1.y,a1.z,a1.w};
      float b[8] = {b0.x,b0.y,b0.z,b0.w,b1.x,b1.y,b1.z,b1.w};
#pragma unroll
      for (int i = 0; i < 8; ++i)
#pragma unroll
        for (int j = 0; j < 8; ++j) acc[i][j] = fmaf(a[i], b[j], acc[i][j]);
    }
  }

#pragma unroll
  for (int i = 0; i < 8; ++i) {
    int m = m0 + ty * 8 + i;
    float* o = pre + (size_t)m * HID + n0 + tx * 8;
#pragma unroll
    for (int j = 0; j < 8; ++j) {
      int n = n0 + tx * 8 + j;
      o[j] = acc[i][j] + bi0[n] + bh0[n];
    }
  }
}

// ---------------------------------------------------------------------------
// Fused cooperative kernel: r10 decoupled 2-cohort scan + proj scavenging.
//  bar lines (128B): 0..3 L0 arrivals, 4..11 L1 arrivals, 12 go0, 13 go1,
//  14 proj ticket counter.
//  Blocks 0..63   L0 scan (16 rows Wh0), then join proj tickets.
//  Blocks 64..191 L1 scan (8 rows [Wi1|Wh1]); tops stored sc0sc1 (in-kernel
//                 consumers!), drained before arrival; then join tickets.
//  Block 192      master: publishes go0/go1 epochs, then joins tickets.
//  Blocks 193..255 helpers: proj tickets from the start.
//  proj tile (mt,nt): M rows m = mt*256.. (m = t*16+b, contiguous tops rows),
//  ready when go1 >= 16(mt+1); split-bf16 MFMA identical math to r3-r10.
//  C-write: out[((m&15)*256 + (m>>4)) * VOCAB + n].
// ---------------------------------------------------------------------------
__global__ __launch_bounds__(512) void rnn_scan(
    const float* __restrict__ Wi, const float* __restrict__ Wh,
    const float* __restrict__ bi, const float* __restrict__ bh,
    const float* __restrict__ pre0, float* __restrict__ h0ring,
    float* __restrict__ h1g, float* __restrict__ tops,
    const float* __restrict__ Wo, const float* __restrict__ bo,
    float* __restrict__ out, int* __restrict__ bar)
{
  __shared__ __align__(16) char pool[139328];   // scan: 136.1KB ; proj: 96KB
  __shared__ int tkt_s;
  const int tid = threadIdx.x;
  const int blk = blockIdx.x;
  int* go0    = bar + 12 * 32;
  int* go1    = bar + 13 * 32;
  int* ticket = bar + 14 * 32;

  // ---------------- proj scavenger (all blocks eventually run this) --------
  auto proj_tiles = [&]() {
    ushort* Ahi = (ushort*)pool;
    ushort* Alo = Ahi + 16384;
    ushort* Bs  = Alo + 16384;
    const int lane = tid & 63, wv = tid >> 6;
    const int wm = wv & 3, wn = wv >> 2;
    const int sr = tid >> 4;
    const int sk = (tid & 15) * 4;
    for (;;) {
      if (tid == 0)
        tkt_s = __hip_atomic_fetch_add(ticket, 1, __ATOMIC_RELAXED,
                                       __HIP_MEMORY_SCOPE_AGENT);
      __syncthreads();
      const int T = tkt_s;
      if (T >= NTILES) break;
      const int mt = T / NTILE_N, nt = T % NTILE_N;
      if (tid == 0) {
        int need = 16 * (mt + 1); if (need > SEQ) need = SEQ;
        while (ld_rlx(go1) < need) __builtin_amdgcn_s_sleep(2);
      }
      __syncthreads();                       // gate passed; also guards tkt_s
      const int m0 = mt * 256, n0 = nt * 256;

      f32x4 acc[4][8];
#pragma unroll
      for (int i = 0; i < 4; ++i)
#pragma unroll
        for (int j = 0; j < 8; ++j) acc[i][j] = (f32x4)0.f;

      for (int kt = 0; kt < HID; kt += 64) {
        __syncthreads();
#pragma unroll
        for (int p = 0; p < 8; ++p) {        // stage A (contiguous tops rows)
          int r = sr + 32 * p;
          float4 v = *(const float4*)(tops + (size_t)(m0 + r) * HID + kt + sk);
          float f[4] = {v.x, v.y, v.z, v.w};
          ushort hi[4], lo[4];
#pragma unroll
          for (int c = 0; c < 4; ++c) {
            hi[c] = f2bf(f[c]);
            lo[c] = f2bf(f[c] - bf2f(hi[c]));
          }
          uint off = (uint)(r * 128 + sk * 2) ^ (uint)((r & 7) << 4);
          *(ushort4*)((char*)Ahi + off) = make_ushort4(hi[0], hi[1], hi[2], hi[3]);
          *(ushort4*)((char*)Alo + off) = make_ushort4(lo[0], lo[1], lo[2], lo[3]);
        }
#pragma unroll
        for (int p = 0; p < 8; ++p) {        // stage B (Wo rows -> bf16)
          int r = sr + 32 * p;
          float4 v = *(const float4*)(Wo + (size_t)(n0 + r) * HID + kt + sk);
          uint off = (uint)(r * 128 + sk * 2) ^ (uint)((r & 7) << 4);
          *(ushort4*)((char*)Bs + off) =
              make_ushort4(f2bf(v.x), f2bf(v.y), f2bf(v.z), f2bf(v.w));
        }
        __syncthreads();

        const int fr = lane & 15, kg = lane >> 4;
#pragma unroll
        for (int kk = 0; kk < 2; ++kk) {
          short8 bf[8], ah[4], al[4];
#pragma unroll
          for (int nf = 0; nf < 8; ++nf) {
            int row = wn * 128 + nf * 16 + fr;
            uint off = (uint)(row * 128 + kk * 64 + kg * 16) ^ (uint)((row & 7) << 4);
            bf[nf] = *(const short8*)((const char*)Bs + off);
          }
#pragma unroll
          for (int mf = 0; mf < 4; ++mf) {
            int row = wm * 64 + mf * 16 + fr;
            uint off = (uint)(row * 128 + kk * 64 + kg * 16) ^ (uint)((row & 7) << 4);
            ah[mf] = *(const short8*)((const char*)Ahi + off);
            al[mf] = *(const short8*)((const char*)Alo + off);
          }
#pragma unroll
          for (int mf = 0; mf < 4; ++mf)
#pragma unroll
            for (int nf = 0; nf < 8; ++nf) {
              acc[mf][nf] = __builtin_amdgcn_mfma_f32_16x16x32_bf16(
                  ah[mf], bf[nf], acc[mf][nf], 0, 0, 0);
              acc[mf][nf] = __builtin_amdgcn_mfma_f32_16x16x32_bf16(
                  al[mf], bf[nf], acc[mf][nf], 0, 0, 0);
            }
        }
      }

      const int fr = lane & 15, rg = lane >> 4;
#pragma unroll
      for (int mf = 0; mf < 4; ++mf)
#pragma unroll
        for (int nf = 0; nf < 8; ++nf) {
          int n = n0 + wn * 128 + nf * 16 + fr;
          float bb = bo[n];
#pragma unroll
          for (int j = 0; j < 4; ++j) {
            int m = m0 + wm * 64 + mf * 16 + rg * 4 + j;
            int orow = (m & 15) * 256 + (m >> 4);      // [b][s] row
            out[(size_t)orow * VOCAB + n] = acc[mf][nf][j] + bb;
          }
        }
    }
  };

  // -------------------- master + helpers ----------------------------------
  if (blk >= MASTER) {
    if (blk == MASTER && tid == 0) {         // epoch publisher
      int e0 = 0, e1 = 0;
      while (e0 < SEQ || e1 < SEQ) {
        int s0 = 0, s1 = 0;
#pragma unroll
        for (int i = 0; i < 4; ++i) s0 += ld_rlx(bar + i * 32);
#pragma unroll
        for (int i = 0; i < 8; ++i) s1 += ld_rlx(bar + (4 + i) * 32);
        int n0 = s0 >> 6;
        int n1 = s1 >> 7;
        if (n0 > e0) { e0 = n0; st_rlx(go0, e0); }
        if (n1 > e1) { e1 = n1; st_rlx(go1, e1); }
      }
    }
    proj_tiles();                            // helpers immediately; master after
    return;
  }

  // -------------------- scan blocks (r10 flow) -----------------------------
  float* wT   = (float*)pool;                // 16384 floats
  float* hT   = wT + 16384;                  // 16384 floats
  float* part = hT + 16384;                  // 2048 floats
  float* bias = part + 2048;                 // 8 floats

  const bool isL0 = (blk < NL0);

  if (isL0) {
    const int j = blk;
#pragma unroll
    for (int p = 0; p < 8; ++p) {
      int idx = tid + 512 * p;
      int r = idx >> 8, kq = idx & 255;
      float4 v = *(const float4*)(Wh + ((size_t)(16 * j + r)) * HID + 4 * kq);
      wT[(4*kq+0)*16 + r] = v.x; wT[(4*kq+1)*16 + r] = v.y;
      wT[(4*kq+2)*16 + r] = v.z; wT[(4*kq+3)*16 + r] = v.w;
    }
  } else {
    const int j = blk - NL0;
#pragma unroll
    for (int p = 0; p < 8; ++p) {
      int idx = tid + 512 * p;
      int half = idx >> 11;
      int id2 = idx & 2047;
      int r = id2 >> 8, kq = id2 & 255;
      const float* W = (half ? Wh : Wi) + (size_t)HID * HID;
      float4 v = *(const float4*)(W + ((size_t)(8 * j + r)) * HID + 4 * kq);
      int kb = half * 1024 + 4 * kq;
      wT[(kb+0)*8 + r] = v.x; wT[(kb+1)*8 + r] = v.y;
      wT[(kb+2)*8 + r] = v.z; wT[(kb+3)*8 + r] = v.w;
    }
    if (tid < 8) bias[tid] = bi[HID + 8 * j + tid] + bh[HID + 8 * j + tid];
  }
  __syncthreads();

  const int sb  = tid & 15;
  const int skq = tid >> 4;
  auto hbase = [&](const float* src) {
    return (const float*)((const char*)src + sb * 4096 + skq * 16);
  };
  auto stage_write = [&](const f32x4* d) {
#pragma unroll
    for (int p = 0; p < 8; ++p) {
      int kq = skq + 32 * p;
#pragma unroll
      for (int c = 0; c < 4; ++c) hT[(4*kq+c)*16 + sb] = d[p][c];
    }
  };

  if (isL0) {
    // =============================== L0 ===================================
    const int bq = tid & 3, rq = (tid >> 2) & 3, ks = tid >> 4;  // ks 0..31
    for (int u = 0; u < SEQ; ++u) {
      float myPre = 0.f;               // gate-independent prefetch
      if (tid < 256)
        myPre = pre0[((size_t)u * BATCH + (tid >> 4)) * HID + 16 * blk + (tid & 15)];

      if (tid == 0) {
        while (ld_rlx(go0) < u) __builtin_amdgcn_s_sleep(1);
        const int need = u - 7;
        if (need > 0)
          while (ld_rlx(go1) < need) __builtin_amdgcn_s_sleep(1);
      }
      __syncthreads();

      f32x4 r0[8];
      LOAD8(r0, hbase(h0ring + ((u - 1) & 7) * BH));
      WAIT8(r0);
      stage_write(r0);
      __syncthreads();

      float acc[4][4] = {{0.f}};
#pragma unroll 4
      for (int i = 0; i < 32; ++i) {
        int k = ks + 32 * i;
        float4 hv = *(const float4*)&hT[k * 16 + 4 * bq];
        float4 wv = *(const float4*)&wT[k * 16 + 4 * rq];
        float hb[4] = {hv.x, hv.y, hv.z, hv.w};
        float wr[4] = {wv.x, wv.y, wv.z, wv.w};
#pragma unroll
        for (int b_ = 0; b_ < 4; ++b_)
#pragma unroll
          for (int rj = 0; rj < 4; ++rj)
            acc[b_][rj] = fmaf(hb[b_], wr[rj], acc[b_][rj]);
      }
#pragma unroll
      for (int b_ = 0; b_ < 4; ++b_)
#pragma unroll
        for (int rj = 0; rj < 4; ++rj) {
          float v = acc[b_][rj];
          v += __shfl_xor(v, 16); v += __shfl_xor(v, 32);
          acc[b_][rj] = v;
        }
      const int w = tid >> 6;
      if ((tid & 63) < 16) {
#pragma unroll
        for (int b_ = 0; b_ < 4; ++b_)
#pragma unroll
          for (int rj = 0; rj < 4; ++rj)
            part[w * 256 + (4*bq + b_) * 16 + 4*rq + rj] = acc[b_][rj];
      }
      __syncthreads();
      if (tid < 256) {
        int b = tid >> 4, r = tid & 15;
        float s = myPre;
#pragma unroll
        for (int w2 = 0; w2 < 8; ++w2) s += part[w2 * 256 + b * 16 + r];
        st_coherent(h0ring + (u & 7) * BH + (size_t)b * HID + 16 * blk + r, tanhf(s));
      }
      asm volatile("s_waitcnt vmcnt(0)" ::: "memory");
      __syncthreads();
      if (tid == 0)
        __hip_atomic_fetch_add(bar + (blk & 3) * 32, 1,
                               __ATOMIC_RELAXED, __HIP_MEMORY_SCOPE_AGENT);
    }
  } else {
    // =============================== L1 ===================================
    const int bq = tid & 3, rq = (tid >> 2) & 1, ks = tid >> 3;  // ks 0..63
    for (int t = 0; t < SEQ; ++t) {
      // ---- phase A (off critical chain): Wi1 . h0[t] ----
      if (tid == 0)
        while (ld_rlx(go0) < t + 1) __builtin_amdgcn_s_sleep(1);
      __syncthreads();

      f32x4 r0[8];
      LOAD8(r0, hbase(h0ring + (t & 7) * BH));
      WAIT8(r0);
      stage_write(r0);
      __syncthreads();

      float acc[4][4] = {{0.f}};
#pragma unroll 4
      for (int i = 0; i < 16; ++i) {
        int k = ks + 64 * i;
        float4 hv = *(const float4*)&hT[k * 16 + 4 * bq];
        float4 wv = *(const float4*)&wT[k * 8 + 4 * rq];
        float hb[4] = {hv.x, hv.y, hv.z, hv.w};
        float wr[4] = {wv.x, wv.y, wv.z, wv.w};
#pragma unroll
        for (int b_ = 0; b_ < 4; ++b_)
#pragma unroll
          for (int rj = 0; rj < 4; ++rj)
            acc[b_][rj] = fmaf(hb[b_], wr[rj], acc[b_][rj]);
      }

      // ---- serial gate: h1[t-1] ready ----
      if (tid == 0 && t)
        while (ld_rlx(go1) < t) __builtin_amdgcn_s_sleep(1);
      __syncthreads();                 // gate passed AND all done reading hT

      f32x4 r1[8];
      LOAD8(r1, hbase(h1g + ((t - 1) & 1) * BH));
      WAIT8(r1);
      stage_write(r1);
      __syncthreads();

      // ---- phase B: Wh1 . h1[t-1] ----
#pragma unroll 4
      for (int i = 0; i < 16; ++i) {
        int k = ks + 64 * i;
        float4 hv = *(const float4*)&hT[k * 16 + 4 * bq];
        float4 wv = *(const float4*)&wT[(1024 + k) * 8 + 4 * rq];
        float hb[4] = {hv.x, hv.y, hv.z, hv.w};
        float wr[4] = {wv.x, wv.y, wv.z, wv.w};
#pragma unroll
        for (int b_ = 0; b_ < 4; ++b_)
#pragma unroll
          for (int rj = 0; rj < 4; ++rj)
            acc[b_][rj] = fmaf(hb[b_], wr[rj], acc[b_][rj]);
      }
#pragma unroll
      for (int b_ = 0; b_ < 4; ++b_)
#pragma unroll
        for (int rj = 0; rj < 4; ++rj) {
          float v = acc[b_][rj];
          v += __shfl_xor(v, 8); v += __shfl_xor(v, 16); v += __shfl_xor(v, 32);
          acc[b_][rj] = v;
        }
      const int w = tid >> 6;
      if ((tid & 63) < 8) {
#pragma unroll
        for (int b_ = 0; b_ < 4; ++b_)
#pragma unroll
          for (int rj = 0; rj < 4; ++rj)
            part[w * 128 + (4*bq + b_) * 8 + 4*rq + rj] = acc[b_][rj];
      }
      __syncthreads();
      if (tid < 128) {
        int b = tid >> 3, r = tid & 7;
        float s = bias[r];
#pragma unroll
        for (int w2 = 0; w2 < 8; ++w2) s += part[w2 * 128 + b * 8 + r];
        int R = 8 * (blk - NL0) + r;
        float v = tanhf(s);
        // tops now has IN-KERNEL consumers (proj scavengers) -> MALL-coherent
        st_coherent(&tops[((size_t)t * BATCH + b) * HID + R], v);
        st_coherent(h1g + (t & 1) * BH + (size_t)b * HID + R, v);
      }
      asm volatile("s_waitcnt vmcnt(0)" ::: "memory");
      __syncthreads();
      if (tid == 0)
        __hip_atomic_fetch_add(bar + (4 + (blk & 7)) * 32, 1,
                               __ATOMIC_RELAXED, __HIP_MEMORY_SCOPE_AGENT);
    }
  }

  // scan done for this block -> join the proj ticket queue
  __syncthreads();
  proj_tiles();
}

// hidden[0][b][n] = h0 step 255 (ring slot 7); hidden[1] = tops[255]
__global__ void copy_hidden(const float* __restrict__ h0ring,
                            const float* __restrict__ tops,
                            float* __restrict__ outh)
{
  int i = blockIdx.x * 256 + threadIdx.x;   // 0..32767
  int l = i >> 14, rem = i & 16383;
  outh[i] = (l == 0) ? h0ring[7 * BH + rem]
                     : tops[(size_t)(SEQ - 1) * BH + rem];
}

extern "C" void kernel_launch(void* const* d_in, const int* in_sizes, int n_in,
                              void* d_out, int out_size, void* d_ws, size_t ws_size,
                              hipStream_t stream)
{
  const int*   x     = (const int*)d_in[0];
  const float* embed = (const float*)d_in[1];
  const float* Wi    = (const float*)d_in[2];
  const float* bi    = (const float*)d_in[3];
  const float* Wh    = (const float*)d_in[4];
  const float* bh    = (const float*)d_in[5];
  const float* Wo    = (const float*)d_in[6];
  const float* bo    = (const float*)d_in[7];
  float* out = (float*)d_out;

  char* ws = (char*)d_ws;
  float* pre0   = (float*)(ws);                           // 16 MiB [t][b][n]
  float* tops   = (float*)(ws + (16u << 20));             // 16 MiB [t][b][n]
  float* h0ring = (float*)(ws + (32u << 20));             // 8 x 64 KiB ring
  float* h1g    = (float*)(ws + (32u << 20) + 524288);    // 2 x 64 KiB
  int*   bar    = (int*)  (ws + (32u << 20) + 655360);    // arrivals/go/ticket

  // zero ring + h1 parities + counters (deterministic across replays)
  hipMemsetAsync(h0ring, 0, 655360 + 4096, stream);

  pre0_gemm<<<dim3(8, 32), dim3(256), 0, stream>>>(x, embed, Wi, bi, bh, pre0);

  void* args[] = { (void*)&Wi, (void*)&Wh, (void*)&bi, (void*)&bh,
                   (void*)&pre0, (void*)&h0ring, (void*)&h1g, (void*)&tops,
                   (void*)&Wo, (void*)&bo, (void*)&out, (void*)&bar };
  hipLaunchCooperativeKernel((void*)rnn_scan, dim3(NBLK), dim3(512), args, 0, stream);

  copy_hidden<<<dim3(128), dim3(256), 0, stream>>>(
      h0ring, tops, out + (size_t)BATCH * SEQ * VOCAB);
}

// Round 12
// 2332.842 us; speedup vs baseline: 2.8104x; 1.2005x over previous
//
#include <hip/hip_runtime.h>
#include <cmath>
#include <cstdint>

#define VOCAB 32000
#define HID   1024
#define BATCH 16
#define SEQ   256
#define NL0   64
#define NL1   128
#define MASTER 192                 // block 192: sync master (then scavenges)
#define NBLK  256                  // 64 L0 + 128 L1 + 1 master + 63 helpers
#define BH    (BATCH * HID)
#define NTILE_M 16
#define NTILE_N 125
#define NTILES  (NTILE_M * NTILE_N)   // 2000 proj tiles (256x256)

typedef __attribute__((ext_vector_type(8))) short short8;
typedef __attribute__((ext_vector_type(4))) float f32x4;

__device__ __forceinline__ ushort f2bf(float f) {  // RNE fp32 -> bf16 bits
  uint u = __builtin_bit_cast(uint, f);
  return (ushort)((u + 0x7FFFu + ((u >> 16) & 1u)) >> 16);
}
__device__ __forceinline__ float bf2f(ushort h) {
  return __builtin_bit_cast(float, (uint)h << 16);
}

// ---- MALL-coherent vector load/store (sc0 sc1), early-clobber outputs ----
#define LOAD8(d, base)                                                        \
  asm volatile(                                                               \
    "global_load_dwordx4 %0, %8, off sc0 sc1\n\t"                             \
    "global_load_dwordx4 %1, %8, off offset:512 sc0 sc1\n\t"                  \
    "global_load_dwordx4 %2, %8, off offset:1024 sc0 sc1\n\t"                 \
    "global_load_dwordx4 %3, %8, off offset:1536 sc0 sc1\n\t"                 \
    "global_load_dwordx4 %4, %8, off offset:2048 sc0 sc1\n\t"                 \
    "global_load_dwordx4 %5, %8, off offset:2560 sc0 sc1\n\t"                 \
    "global_load_dwordx4 %6, %8, off offset:3072 sc0 sc1\n\t"                 \
    "global_load_dwordx4 %7, %8, off offset:3584 sc0 sc1"                     \
    : "=&v"(d[0]), "=&v"(d[1]), "=&v"(d[2]), "=&v"(d[3]),                     \
      "=&v"(d[4]), "=&v"(d[5]), "=&v"(d[6]), "=&v"(d[7])                      \
    : "v"(base) : "memory")

#define WAIT8(d)                                                              \
  asm volatile("s_waitcnt vmcnt(0)"                                           \
    : "+v"(d[0]), "+v"(d[1]), "+v"(d[2]), "+v"(d[3]),                         \
      "+v"(d[4]), "+v"(d[5]), "+v"(d[6]), "+v"(d[7]) :: "memory")

__device__ __forceinline__ void st_coherent(float* p, float v) {
  asm volatile("global_store_dword %0, %1, off sc0 sc1" :: "v"(p), "v"(v) : "memory");
}
__device__ __forceinline__ void st_coherent_u16(ushort* p, ushort v) {
  asm volatile("global_store_short %0, %1, off sc0 sc1" :: "v"(p), "v"((uint)v) : "memory");
}
__device__ __forceinline__ int ld_rlx(const int* p) {
  return __hip_atomic_load(p, __ATOMIC_RELAXED, __HIP_MEMORY_SCOPE_AGENT);
}
__device__ __forceinline__ void st_rlx(int* p, int v) {
  __hip_atomic_store(p, v, __ATOMIC_RELAXED, __HIP_MEMORY_SCOPE_AGENT);
}

// ---------------------------------------------------------------------------
// pre0[t][b][n] = embed[x[b][t]] . Wi0[n] + bi0[n] + bh0[n]   (unchanged)
// ---------------------------------------------------------------------------
__global__ __launch_bounds__(256) void pre0_gemm(
    const int* __restrict__ x, const float* __restrict__ embed,
    const float* __restrict__ Wi0, const float* __restrict__ bi0,
    const float* __restrict__ bh0, float* __restrict__ pre)
{
  __shared__ float As[32][132];
  __shared__ float Bs[32][132];
  const int tid  = threadIdx.x;
  const int n0   = blockIdx.x * 128;
  const int m0   = blockIdx.y * 128;
  const int lrow = tid >> 3, lkq = tid & 7;
  const int ty   = tid >> 4, tx  = tid & 15;

  const float* arow[4];
#pragma unroll
  for (int q = 0; q < 4; ++q) {
    int m = m0 + lrow + 32 * q;
    int t = m >> 4, b = m & 15;
    arow[q] = embed + (size_t)x[b * SEQ + t] * HID;
  }
  const float* brow = Wi0 + (size_t)(n0 + lrow) * HID;

  float acc[8][8];
#pragma unroll
  for (int i = 0; i < 8; ++i)
#pragma unroll
    for (int j = 0; j < 8; ++j) acc[i][j] = 0.f;

  for (int kt = 0; kt < HID; kt += 32) {
    float4 av[4], bv[4];
#pragma unroll
    for (int q = 0; q < 4; ++q) {
      av[q] = *(const float4*)(arow[q] + kt + lkq * 4);
      bv[q] = *(const float4*)(brow + (size_t)(32 * q) * HID + kt + lkq * 4);
    }
    __syncthreads();
#pragma unroll
    for (int q = 0; q < 4; ++q) {
      int r = lrow + 32 * q;
      As[lkq*4+0][r] = av[q].x; As[lkq*4+1][r] = av[q].y;
      As[lkq*4+2][r] = av[q].z; As[lkq*4+3][r] = av[q].w;
      Bs[lkq*4+0][r] = bv[q].x; Bs[lkq*4+1][r] = bv[q].y;
      Bs[lkq*4+2][r] = bv[q].z; Bs[lkq*4+3][r] = bv[q].w;
    }
    __syncthreads();
#pragma unroll
    for (int kk = 0; kk < 32; ++kk) {
      float4 a0 = *(const float4*)&As[kk][ty * 8];
      float4 a1 = *(const float4*)&As[kk][ty * 8 + 4];
      float4 b0 = *(const float4*)&Bs[kk][tx * 8];
      float4 b1 = *(const float4*)&Bs[kk][tx * 8 + 4];
      float a[8] = {a0.x,a0.y,a0.z,a0.w,a1.x,a1.y,a1.z,a1.w};
      float b[8] = {b0.x,b0.y,b0.z,b0.w,b1.x,b1.y,b1.z,b1.w};
#pragma unroll
      for (int i = 0; i < 8; ++i)
#pragma unroll
        for (int j = 0; j < 8; ++j) acc[i][j] = fmaf(a[i], b[j], acc[i][j]);
    }
  }

#pragma unroll
  for (int i = 0; i < 8; ++i) {
    int m = m0 + ty * 8 + i;
    float* o = pre + (size_t)m * HID + n0 + tx * 8;
#pragma unroll
    for (int j = 0; j < 8; ++j) {
      int n = n0 + tx * 8 + j;
      o[j] = acc[i][j] + bi0[n] + bh0[n];
    }
  }
}

// Wo (f32) -> WoH (bf16 RNE), one-time. 32000*1024 = 32,768,000 elems.
__global__ __launch_bounds__(256) void wo_conv(
    const float* __restrict__ Wo, ushort* __restrict__ WoH)
{
  const size_t total = (size_t)VOCAB * HID;
  for (size_t i = ((size_t)blockIdx.x * 256 + threadIdx.x) * 8; i < total;
       i += (size_t)gridDim.x * 256 * 8) {
    float4 v0 = *(const float4*)(Wo + i);
    float4 v1 = *(const float4*)(Wo + i + 4);
    short8 w;
    w[0] = (short)f2bf(v0.x); w[1] = (short)f2bf(v0.y);
    w[2] = (short)f2bf(v0.z); w[3] = (short)f2bf(v0.w);
    w[4] = (short)f2bf(v1.x); w[5] = (short)f2bf(v1.y);
    w[6] = (short)f2bf(v1.z); w[7] = (short)f2bf(v1.w);
    *(short8*)(WoH + i) = w;
  }
}

// ---------------------------------------------------------------------------
// Fused cooperative kernel: decoupled 2-cohort scan + proj scavenging.
//  bar lines (128B): 0..3 L0 arrivals, 4..11 L1 arrivals, 12..19 go0 replicas,
//  20..27 go1 replicas, 28 proj ticket counter.
//  L1 stores tops pre-split as bf16 hi/lo (identical f2bf math to r3-r11).
//  proj: A staged from topsHi/Lo (no conversion), B from WoH bf16 (or Wo f32
//  fallback when ws too small). Tile (mt,nt) gated on go1 >= 16(mt+1).
// ---------------------------------------------------------------------------
__global__ __launch_bounds__(512) void rnn_scan(
    const float* __restrict__ Wi, const float* __restrict__ Wh,
    const float* __restrict__ bi, const float* __restrict__ bh,
    const float* __restrict__ pre0, float* __restrict__ h0ring,
    float* __restrict__ h1g, ushort* __restrict__ topsHi,
    ushort* __restrict__ topsLo, const float* __restrict__ Wo,
    const ushort* __restrict__ WoH, const float* __restrict__ bo,
    float* __restrict__ out, int* __restrict__ bar)
{
  __shared__ __align__(16) char pool[139328];   // scan 136.1KB ; proj 96KB
  __shared__ int tkt_s;
  const int tid = threadIdx.x;
  const int blk = blockIdx.x;
  const int rep = (blk & 7) * 32;
  int* go0r = bar + 12 * 32 + rep;
  int* go1r = bar + 20 * 32 + rep;
  int* ticket = bar + 28 * 32;

  // ---------------- proj scavenger (all blocks eventually run this) --------
  auto proj_tiles = [&]() {
    ushort* Ahi = (ushort*)pool;               // 32 KiB each
    ushort* Alo = Ahi + 16384;
    ushort* Bs  = Alo + 16384;
    const int lane = tid & 63, wv = tid >> 6;
    const int wm = wv & 3, wn = wv >> 2;
    const int sr8 = tid >> 3;                  // row base 0..63
    const int sk8 = (tid & 7) * 8;             // k offset 0..56
    for (;;) {
      if (tid == 0)
        tkt_s = __hip_atomic_fetch_add(ticket, 1, __ATOMIC_RELAXED,
                                       __HIP_MEMORY_SCOPE_AGENT);
      __syncthreads();
      const int T = tkt_s;
      if (T >= NTILES) break;
      const int mt = T / NTILE_N, nt = T % NTILE_N;
      if (tid == 0) {
        const int need = 16 * (mt + 1);
        while (ld_rlx(go1r) < need) __builtin_amdgcn_s_sleep(4);
      }
      __syncthreads();                         // gate passed; guards tkt_s
      const int m0 = mt * 256, n0 = nt * 256;

      f32x4 acc[4][8];
#pragma unroll
      for (int i = 0; i < 4; ++i)
#pragma unroll
        for (int j = 0; j < 8; ++j) acc[i][j] = (f32x4)0.f;

      for (int kt = 0; kt < HID; kt += 64) {
        __syncthreads();
#pragma unroll
        for (int p = 0; p < 4; ++p) {          // stage A hi/lo + B, no convert
          int r = sr8 + 64 * p;
          uint off = (uint)(r * 128 + sk8 * 2) ^ (uint)((r & 7) << 4);
          *(short8*)((char*)Ahi + off) =
              *(const short8*)(topsHi + (size_t)(m0 + r) * HID + kt + sk8);
          *(short8*)((char*)Alo + off) =
              *(const short8*)(topsLo + (size_t)(m0 + r) * HID + kt + sk8);
          if (WoH) {
            *(short8*)((char*)Bs + off) =
                *(const short8*)(WoH + (size_t)(n0 + r) * HID + kt + sk8);
          } else {
            float4 v0 = *(const float4*)(Wo + (size_t)(n0 + r) * HID + kt + sk8);
            float4 v1 = *(const float4*)(Wo + (size_t)(n0 + r) * HID + kt + sk8 + 4);
            short8 w;
            w[0] = (short)f2bf(v0.x); w[1] = (short)f2bf(v0.y);
            w[2] = (short)f2bf(v0.z); w[3] = (short)f2bf(v0.w);
            w[4] = (short)f2bf(v1.x); w[5] = (short)f2bf(v1.y);
            w[6] = (short)f2bf(v1.z); w[7] = (short)f2bf(v1.w);
            *(short8*)((char*)Bs + off) = w;
          }
        }
        __syncthreads();

        const int fr = lane & 15, kg = lane >> 4;
#pragma unroll
        for (int kk = 0; kk < 2; ++kk) {
          short8 bf[8], ah[4], al[4];
#pragma unroll
          for (int nf = 0; nf < 8; ++nf) {
            int row = wn * 128 + nf * 16 + fr;
            uint off = (uint)(row * 128 + kk * 64 + kg * 16) ^ (uint)((row & 7) << 4);
            bf[nf] = *(const short8*)((const char*)Bs + off);
          }
#pragma unroll
          for (int mf = 0; mf < 4; ++mf) {
            int row = wm * 64 + mf * 16 + fr;
            uint off = (uint)(row * 128 + kk * 64 + kg * 16) ^ (uint)((row & 7) << 4);
            ah[mf] = *(const short8*)((const char*)Ahi + off);
            al[mf] = *(const short8*)((const char*)Alo + off);
          }
#pragma unroll
          for (int mf = 0; mf < 4; ++mf)
#pragma unroll
            for (int nf = 0; nf < 8; ++nf) {
              acc[mf][nf] = __builtin_amdgcn_mfma_f32_16x16x32_bf16(
                  ah[mf], bf[nf], acc[mf][nf], 0, 0, 0);
              acc[mf][nf] = __builtin_amdgcn_mfma_f32_16x16x32_bf16(
                  al[mf], bf[nf], acc[mf][nf], 0, 0, 0);
            }
        }
      }

      const int fr = lane & 15, rg = lane >> 4;
#pragma unroll
      for (int mf = 0; mf < 4; ++mf)
#pragma unroll
        for (int nf = 0; nf < 8; ++nf) {
          int n = n0 + wn * 128 + nf * 16 + fr;
          float bb = bo[n];
#pragma unroll
          for (int j = 0; j < 4; ++j) {
            int m = m0 + wm * 64 + mf * 16 + rg * 4 + j;
            int orow = (m & 15) * 256 + (m >> 4);      // [b][s] row
            out[(size_t)orow * VOCAB + n] = acc[mf][nf][j] + bb;
          }
        }
    }
  };

  // -------------------- master + helpers ----------------------------------
  if (blk >= MASTER) {
    if (blk == MASTER && tid == 0) {           // epoch publisher (replicated)
      int e0 = 0, e1 = 0;
      while (e0 < SEQ || e1 < SEQ) {
        int s0 = 0, s1 = 0;
#pragma unroll
        for (int i = 0; i < 4; ++i) s0 += ld_rlx(bar + i * 32);
#pragma unroll
        for (int i = 0; i < 8; ++i) s1 += ld_rlx(bar + (4 + i) * 32);
        int n0 = s0 >> 6;
        int n1 = s1 >> 7;
        if (n0 > e0) {
          e0 = n0;
#pragma unroll
          for (int i = 0; i < 8; ++i) st_rlx(bar + (12 + i) * 32, e0);
        }
        if (n1 > e1) {
          e1 = n1;
#pragma unroll
          for (int i = 0; i < 8; ++i) st_rlx(bar + (20 + i) * 32, e1);
        }
      }
    }
    proj_tiles();                              // helpers now; master after
    return;
  }

  // -------------------- scan blocks (r10 flow) -----------------------------
  float* wT   = (float*)pool;                  // 16384 floats
  float* hT   = wT + 16384;                    // 16384 floats
  float* part = hT + 16384;                    // 2048 floats
  float* bias = part + 2048;                   // 8 floats

  const bool isL0 = (blk < NL0);

  if (isL0) {
    const int j = blk;
#pragma unroll
    for (int p = 0; p < 8; ++p) {
      int idx = tid + 512 * p;
      int r = idx >> 8, kq = idx & 255;
      float4 v = *(const float4*)(Wh + ((size_t)(16 * j + r)) * HID + 4 * kq);
      wT[(4*kq+0)*16 + r] = v.x; wT[(4*kq+1)*16 + r] = v.y;
      wT[(4*kq+2)*16 + r] = v.z; wT[(4*kq+3)*16 + r] = v.w;
    }
  } else {
    const int j = blk - NL0;
#pragma unroll
    for (int p = 0; p < 8; ++p) {
      int idx = tid + 512 * p;
      int half = idx >> 11;
      int id2 = idx & 2047;
      int r = id2 >> 8, kq = id2 & 255;
      const float* W = (half ? Wh : Wi) + (size_t)HID * HID;
      float4 v = *(const float4*)(W + ((size_t)(8 * j + r)) * HID + 4 * kq);
      int kb = half * 1024 + 4 * kq;
      wT[(kb+0)*8 + r] = v.x; wT[(kb+1)*8 + r] = v.y;
      wT[(kb+2)*8 + r] = v.z; wT[(kb+3)*8 + r] = v.w;
    }
    if (tid < 8) bias[tid] = bi[HID + 8 * j + tid] + bh[HID + 8 * j + tid];
  }
  __syncthreads();

  const int sb  = tid & 15;
  const int skq = tid >> 4;
  auto hbase = [&](const float* src) {
    return (const float*)((const char*)src + sb * 4096 + skq * 16);
  };
  auto stage_write = [&](const f32x4* d) {
#pragma unroll
    for (int p = 0; p < 8; ++p) {
      int kq = skq + 32 * p;
#pragma unroll
      for (int c = 0; c < 4; ++c) hT[(4*kq+c)*16 + sb] = d[p][c];
    }
  };

  if (isL0) {
    // =============================== L0 ===================================
    const int bq = tid & 3, rq = (tid >> 2) & 3, ks = tid >> 4;  // ks 0..31
    for (int u = 0; u < SEQ; ++u) {
      float myPre = 0.f;               // gate-independent prefetch
      if (tid < 256)
        myPre = pre0[((size_t)u * BATCH + (tid >> 4)) * HID + 16 * blk + (tid & 15)];

      if (tid == 0) {
        while (ld_rlx(go0r) < u) __builtin_amdgcn_s_sleep(1);
        const int need = u - 7;
        if (need > 0)
          while (ld_rlx(go1r) < need) __builtin_amdgcn_s_sleep(1);
      }
      __syncthreads();

      f32x4 r0[8];
      LOAD8(r0, hbase(h0ring + ((u - 1) & 7) * BH));
      WAIT8(r0);
      stage_write(r0);
      __syncthreads();

      float acc[4][4] = {{0.f}};
#pragma unroll 4
      for (int i = 0; i < 32; ++i) {
        int k = ks + 32 * i;
        float4 hv = *(const float4*)&hT[k * 16 + 4 * bq];
        float4 wv = *(const float4*)&wT[k * 16 + 4 * rq];
        float hb[4] = {hv.x, hv.y, hv.z, hv.w};
        float wr[4] = {wv.x, wv.y, wv.z, wv.w};
#pragma unroll
        for (int b_ = 0; b_ < 4; ++b_)
#pragma unroll
          for (int rj = 0; rj < 4; ++rj)
            acc[b_][rj] = fmaf(hb[b_], wr[rj], acc[b_][rj]);
      }
#pragma unroll
      for (int b_ = 0; b_ < 4; ++b_)
#pragma unroll
        for (int rj = 0; rj < 4; ++rj) {
          float v = acc[b_][rj];
          v += __shfl_xor(v, 16); v += __shfl_xor(v, 32);
          acc[b_][rj] = v;
        }
      const int w = tid >> 6;
      if ((tid & 63) < 16) {
#pragma unroll
        for (int b_ = 0; b_ < 4; ++b_)
#pragma unroll
          for (int rj = 0; rj < 4; ++rj)
            part[w * 256 + (4*bq + b_) * 16 + 4*rq + rj] = acc[b_][rj];
      }
      __syncthreads();
      if (tid < 256) {
        int b = tid >> 4, r = tid & 15;
        float s = myPre;
#pragma unroll
        for (int w2 = 0; w2 < 8; ++w2) s += part[w2 * 256 + b * 16 + r];
        st_coherent(h0ring + (u & 7) * BH + (size_t)b * HID + 16 * blk + r, tanhf(s));
      }
      asm volatile("s_waitcnt vmcnt(0)" ::: "memory");
      __syncthreads();
      if (tid == 0)
        __hip_atomic_fetch_add(bar + (blk & 3) * 32, 1,
                               __ATOMIC_RELAXED, __HIP_MEMORY_SCOPE_AGENT);
    }
  } else {
    // =============================== L1 ===================================
    const int bq = tid & 3, rq = (tid >> 2) & 1, ks = tid >> 3;  // ks 0..63
    for (int t = 0; t < SEQ; ++t) {
      // ---- phase A (off critical chain): Wi1 . h0[t] ----
      if (tid == 0)
        while (ld_rlx(go0r) < t + 1) __builtin_amdgcn_s_sleep(1);
      __syncthreads();

      f32x4 r0[8];
      LOAD8(r0, hbase(h0ring + (t & 7) * BH));
      WAIT8(r0);
      stage_write(r0);
      __syncthreads();

      float acc[4][4] = {{0.f}};
#pragma unroll 4
      for (int i = 0; i < 16; ++i) {
        int k = ks + 64 * i;
        float4 hv = *(const float4*)&hT[k * 16 + 4 * bq];
        float4 wv = *(const float4*)&wT[k * 8 + 4 * rq];
        float hb[4] = {hv.x, hv.y, hv.z, hv.w};
        float wr[4] = {wv.x, wv.y, wv.z, wv.w};
#pragma unroll
        for (int b_ = 0; b_ < 4; ++b_)
#pragma unroll
          for (int rj = 0; rj < 4; ++rj)
            acc[b_][rj] = fmaf(hb[b_], wr[rj], acc[b_][rj]);
      }

      // ---- serial gate: h1[t-1] ready ----
      if (tid == 0 && t)
        while (ld_rlx(go1r) < t) __builtin_amdgcn_s_sleep(1);
      __syncthreads();                 // gate passed AND all done reading hT

      f32x4 r1[8];
      LOAD8(r1, hbase(h1g + ((t - 1) & 1) * BH));
      WAIT8(r1);
      stage_write(r1);
      __syncthreads();

      // ---- phase B: Wh1 . h1[t-1] ----
#pragma unroll 4
      for (int i = 0; i < 16; ++i) {
        int k = ks + 64 * i;
        float4 hv = *(const float4*)&hT[k * 16 + 4 * bq];
        float4 wv = *(const float4*)&wT[(1024 + k) * 8 + 4 * rq];
        float hb[4] = {hv.x, hv.y, hv.z, hv.w};
        float wr[4] = {wv.x, wv.y, wv.z, wv.w};
#pragma unroll
        for (int b_ = 0; b_ < 4; ++b_)
#pragma unroll
          for (int rj = 0; rj < 4; ++rj)
            acc[b_][rj] = fmaf(hb[b_], wr[rj], acc[b_][rj]);
      }
#pragma unroll
      for (int b_ = 0; b_ < 4; ++b_)
#pragma unroll
        for (int rj = 0; rj < 4; ++rj) {
          float v = acc[b_][rj];
          v += __shfl_xor(v, 8); v += __shfl_xor(v, 16); v += __shfl_xor(v, 32);
          acc[b_][rj] = v;
        }
      const int w = tid >> 6;
      if ((tid & 63) < 8) {
#pragma unroll
        for (int b_ = 0; b_ < 4; ++b_)
#pragma unroll
          for (int rj = 0; rj < 4; ++rj)
            part[w * 128 + (4*bq + b_) * 8 + 4*rq + rj] = acc[b_][rj];
      }
      __syncthreads();
      if (tid < 128) {
        int b = tid >> 3, r = tid & 7;
        float s = bias[r];
#pragma unroll
        for (int w2 = 0; w2 < 8; ++w2) s += part[w2 * 128 + b * 8 + r];
        int R = 8 * (blk - NL0) + r;
        float v = tanhf(s);
        // tops pre-split to bf16 hi/lo (same f2bf math proj used before)
        ushort hi = f2bf(v);
        ushort lo = f2bf(v - bf2f(hi));
        size_t mi = ((size_t)t * BATCH + b) * HID + R;
        st_coherent_u16(topsHi + mi, hi);
        st_coherent_u16(topsLo + mi, lo);
        st_coherent(h1g + (t & 1) * BH + (size_t)b * HID + R, v);
      }
      asm volatile("s_waitcnt vmcnt(0)" ::: "memory");
      __syncthreads();
      if (tid == 0)
        __hip_atomic_fetch_add(bar + (4 + (blk & 7)) * 32, 1,
                               __ATOMIC_RELAXED, __HIP_MEMORY_SCOPE_AGENT);
    }
  }

  // scan done for this block -> join the proj ticket queue
  __syncthreads();
  proj_tiles();
}

// hidden[0][b][n] = h0 step 255 (ring slot 7); hidden[1] = tops[255] (hi+lo)
__global__ void copy_hidden(const float* __restrict__ h0ring,
                            const ushort* __restrict__ topsHi,
                            const ushort* __restrict__ topsLo,
                            float* __restrict__ outh)
{
  int i = blockIdx.x * 256 + threadIdx.x;   // 0..32767
  int l = i >> 14, rem = i & 16383;         // rem = b*1024 + n
  if (l == 0) {
    outh[i] = h0ring[7 * BH + rem];
  } else {
    size_t mi = (size_t)(SEQ - 1) * BH + rem;
    outh[i] = bf2f(topsHi[mi]) + bf2f(topsLo[mi]);
  }
}

extern "C" void kernel_launch(void* const* d_in, const int* in_sizes, int n_in,
                              void* d_out, int out_size, void* d_ws, size_t ws_size,
                              hipStream_t stream)
{
  const int*   x     = (const int*)d_in[0];
  const float* embed = (const float*)d_in[1];
  const float* Wi    = (const float*)d_in[2];
  const float* bi    = (const float*)d_in[3];
  const float* Wh    = (const float*)d_in[4];
  const float* bh    = (const float*)d_in[5];
  const float* Wo    = (const float*)d_in[6];
  const float* bo    = (const float*)d_in[7];
  float* out = (float*)d_out;

  char* ws = (char*)d_ws;
  float*  pre0   = (float*) (ws);                          // 16 MiB
  ushort* topsHi = (ushort*)(ws + (16u << 20));            // 8 MiB
  ushort* topsLo = (ushort*)(ws + (24u << 20));            // 8 MiB
  float*  h0ring = (float*) (ws + (32u << 20));            // 512 KiB ring
  float*  h1g    = (float*) (ws + (32u << 20) + 524288);   // 128 KiB
  int*    bar    = (int*)   (ws + (32u << 20) + 655360);   // 4 KiB counters
  ushort* WoH    = (ushort*)(ws + (33u << 20));            // 64 MiB (optional)
  const size_t need_woh = (33ull << 20) + (size_t)VOCAB * HID * 2;
  const bool useWoH = ws_size >= need_woh;

  // zero ring + h1 parities + counters (deterministic across replays)
  hipMemsetAsync(h0ring, 0, 659456, stream);

  pre0_gemm<<<dim3(8, 32), dim3(256), 0, stream>>>(x, embed, Wi, bi, bh, pre0);
  if (useWoH)
    wo_conv<<<dim3(2048), dim3(256), 0, stream>>>(Wo, WoH);

  const ushort* WoHArg = useWoH ? WoH : (const ushort*)nullptr;
  void* args[] = { (void*)&Wi, (void*)&Wh, (void*)&bi, (void*)&bh,
                   (void*)&pre0, (void*)&h0ring, (void*)&h1g,
                   (void*)&topsHi, (void*)&topsLo, (void*)&Wo,
                   (void*)&WoHArg, (void*)&bo, (void*)&out, (void*)&bar };
  hipLaunchCooperativeKernel((void*)rnn_scan, dim3(NBLK), dim3(512), args, 0, stream);

  copy_hidden<<<dim3(128), dim3(256), 0, stream>>>(
      h0ring, topsHi, topsLo, out + (size_t)BATCH * SEQ * VOCAB);
}